// Round 1
// baseline (457.585 us; speedup 1.0000x reference)
//
#include <hip/hip_runtime.h>
#include <math.h>

#define N_PTS 8192
#define KNB   64
#define BATCH 4

// ws layout (floats) — BN-folded, transposed weights: WT[c*out_c + o]
#define OFF_W1T   0        // [195][128]
#define OFF_B1    24960    // [128]
#define OFF_W2AT  25088    // [128][64]
#define OFF_B2A   33280    // [64]
#define OFF_W2BT  33344    // [64][64]
#define OFF_B2B   37440    // [64]
#define OFF_LINT  37504    // [64][64]
#define OFF_LINB  41600    // [64]
#define OFF_W3AT  41664    // [128][64]
#define OFF_B3A   49856    // [64]
#define OFF_W3BT  49920    // [64][64]
#define OFF_B3B   54016    // [64]
#define OFF_PNT   54080    // [67][128]
#define OFF_BPN   62656    // [128]

// output offsets (floats)
#define OUT1 32768                    // deep_similarity [4][8192]
#define OUT2 65536                    // shallowrealfeat [4][64][8192]
#define OUT3 (65536 + 2097152)        // deeprealfeat    [4][128][8192]

__global__ void prep_weights(const float* __restrict__ W, const float* __restrict__ b,
                             const float* __restrict__ g, const float* __restrict__ bt,
                             float* __restrict__ WT, float* __restrict__ bout,
                             int in_c, int out_c, int has_bn) {
    int t = blockIdx.x * 256 + threadIdx.x;
    int total = in_c * out_c;
    if (t < total) {
        int o = t % out_c;
        int c = t / out_c;
        float s = has_bn ? g[o] : 1.0f;
        WT[t] = W[o * in_c + c] * s;
    }
    if (t < out_c) {
        bout[t] = has_bn ? (g[t] * b[t] + bt[t]) : b[t];
    }
}

__global__ __launch_bounds__(256)
void fused_mvp(const float* __restrict__ img,   // [4][3][8192][64]
               const float* __restrict__ knn,   // [4][3][64][8192]
               const float* __restrict__ pts,   // [4][3][8192]
               const float* __restrict__ f2d,   // [4][64][8192]
               const float* __restrict__ fw1p, const float* __restrict__ fw2p,
               const float* __restrict__ fw3p,
               const float* __restrict__ ws, float* __restrict__ out)
{
    __shared__ float  xr[4][195];
    __shared__ float  xi[4][195];
    __shared__ float4 if4s[4][64];
    __shared__ float  ya[4][128];
    __shared__ float  yb[4][128];
    __shared__ float  y3r[4][64];

    const int tid  = threadIdx.x;
    const int wid  = tid >> 6;
    const int lane = tid & 63;
    const int p    = blockIdx.x * 4 + wid;   // point id in [0, 32768)
    const int b    = p >> 13;                // / 8192
    const int n    = p & (N_PTS - 1);

    const float* W1T  = ws + OFF_W1T;   const float* B1   = ws + OFF_B1;
    const float* W2AT = ws + OFF_W2AT;  const float* B2A  = ws + OFF_B2A;
    const float* W2BT = ws + OFF_W2BT;  const float* B2B  = ws + OFF_B2B;
    const float* LINT = ws + OFF_LINT;  const float* LINB = ws + OFF_LINB;
    const float* W3AT = ws + OFF_W3AT;  const float* B3A  = ws + OFF_B3A;
    const float* W3BT = ws + OFF_W3BT;  const float* B3B  = ws + OFF_B3B;
    const float* PNT  = ws + OFF_PNT;   const float* BPN  = ws + OFF_BPN;

    // ---- stage neighbor sets ----
    size_t imgBase = ((size_t)(b * 3) * N_PTS + n) * KNB;
    float ix = img[imgBase + lane];
    float iy = img[imgBase + (size_t)N_PTS * KNB + lane];
    float iz = img[imgBase + 2 * (size_t)N_PTS * KNB + lane];
    size_t knnBase = (size_t)(b * 3) * KNB * N_PTS + n;
    float rx = knn[knnBase + (size_t)lane * N_PTS];
    float ry = knn[knnBase + (size_t)(KNB + lane) * N_PTS];
    float rz = knn[knnBase + (size_t)(2 * KNB + lane) * N_PTS];

    xi[wid][3 + lane] = ix;  xi[wid][67 + lane] = iy;  xi[wid][131 + lane] = iz;
    xr[wid][3 + lane] = rx;  xr[wid][67 + lane] = ry;  xr[wid][131 + lane] = rz;
    if (lane < 3) {
        float pv = pts[(size_t)(b * 3 + lane) * N_PTS + n];
        xr[wid][lane] = pv;
        xi[wid][lane] = pv;
    }
    float i2 = ix * ix + iy * iy + iz * iz;
    if4s[wid][lane] = make_float4(ix, iy, iz, i2);
    float r2 = rx * rx + ry * ry + rz * rz;
    __syncthreads();

    // ---- min pairwise distance (lane = real k, loop over image l) ----
    float dmin = 3.0e38f;
    #pragma unroll 8
    for (int l = 0; l < 64; ++l) {
        float4 v = if4s[wid][l];
        float cr = fmaf(rx, v.x, fmaf(ry, v.y, rz * v.z));
        float d  = r2 + v.w - 2.0f * cr;
        dmin = fminf(dmin, d);
    }
    for (int off = 32; off > 0; off >>= 1)
        dmin = fminf(dmin, __shfl_xor(dmin, off, 64));

    // ---- shallow chain, real then image ----
    float sr = 0.0f, si = 0.0f;
    for (int rep = 0; rep < 2; ++rep) {
        const float* xs = rep ? xi[wid] : xr[wid];

        // L1: 195 -> 128
        float a0 = B1[lane], a1 = B1[64 + lane];
        for (int c = 0; c < 195; ++c) {
            float xc = xs[c];
            const float* wr = W1T + c * 128;
            a0 = fmaf(wr[lane], xc, a0);
            a1 = fmaf(wr[64 + lane], xc, a1);
        }
        a0 = fmaxf(a0, 0.0f); a1 = fmaxf(a1, 0.0f);
        ya[wid][lane] = a0; ya[wid][64 + lane] = a1;
        __syncthreads();

        // L2: 128 -> 64
        float a = B2A[lane];
        #pragma unroll 4
        for (int c = 0; c < 128; ++c)
            a = fmaf(W2AT[c * 64 + lane], ya[wid][c], a);
        a = fmaxf(a, 0.0f);
        yb[wid][lane] = a;
        __syncthreads();

        // L3: 64 -> 64
        float a3 = B2B[lane];
        #pragma unroll 4
        for (int c = 0; c < 64; ++c)
            a3 = fmaf(W2BT[c * 64 + lane], yb[wid][c], a3);
        a3 = fmaxf(a3, 0.0f);
        if (rep == 0) {
            y3r[wid][lane] = a3;
            out[OUT2 + (size_t)(b * 64 + lane) * N_PTS + n] = a3;
        } else {
            ya[wid][lane] = a3;
        }
        __syncthreads();

        // lin1: 64 -> 64 (no BN, no relu)
        const float* ysrc = rep ? ya[wid] : y3r[wid];
        float s = LINB[lane];
        #pragma unroll 4
        for (int c = 0; c < 64; ++c)
            s = fmaf(LINT[c * 64 + lane], ysrc[c], s);
        if (rep == 0) sr = s; else si = s;
    }

    // ---- cosine similarity (butterfly: all lanes end with the sums) ----
    float pnum = sr * si, prr = sr * sr, pii = si * si;
    for (int off = 32; off > 0; off >>= 1) {
        pnum += __shfl_xor(pnum, off, 64);
        prr  += __shfl_xor(prr,  off, 64);
        pii  += __shfl_xor(pii,  off, 64);
    }
    float den = fmaxf(sqrtf(prr) * sqrtf(pii), 1e-8f);
    float geo = expf(-(1.0f / fw1p[0]) * dmin) + fw2p[0];
    float sim = (pnum / den) * geo;
    if (lane == 0) {
        out[(size_t)b * N_PTS + n]        = sim;
        out[OUT1 + (size_t)b * N_PTS + n] = fw3p[0];
    }

    // ---- fused = [shallowrealfeat ; sim * feature_2d3d] ----
    float f = sim * f2d[(size_t)(b * 64 + lane) * N_PTS + n];
    __syncthreads();
    ya[wid][lane]      = y3r[wid][lane];
    ya[wid][64 + lane] = f;
    __syncthreads();

    // c3_1: 128 -> 64
    float a = B3A[lane];
    #pragma unroll 4
    for (int c = 0; c < 128; ++c)
        a = fmaf(W3AT[c * 64 + lane], ya[wid][c], a);
    a = fmaxf(a, 0.0f);
    yb[wid][lane] = a;
    __syncthreads();

    // c3_2: 64 -> 64
    float a2 = B3B[lane];
    #pragma unroll 4
    for (int c = 0; c < 64; ++c)
        a2 = fmaf(W3BT[c * 64 + lane], yb[wid][c], a2);
    a2 = fmaxf(a2, 0.0f);

    // deep_in = [points(3); fused(64)]
    ya[wid][3 + lane] = a2;
    if (lane < 3) ya[wid][lane] = pts[(size_t)(b * 3 + lane) * N_PTS + n];
    __syncthreads();

    // pn2: 67 -> 128
    float p0 = BPN[lane], p1 = BPN[64 + lane];
    for (int c = 0; c < 67; ++c) {
        float xc = ya[wid][c];
        const float* wr = PNT + c * 128;
        p0 = fmaf(wr[lane], xc, p0);
        p1 = fmaf(wr[64 + lane], xc, p1);
    }
    p0 = fmaxf(p0, 0.0f); p1 = fmaxf(p1, 0.0f);
    out[OUT3 + (size_t)(b * 128 + lane) * N_PTS + n]      = p0;
    out[OUT3 + (size_t)(b * 128 + 64 + lane) * N_PTS + n] = p1;
}

extern "C" void kernel_launch(void* const* d_in, const int* in_sizes, int n_in,
                              void* d_out, int out_size, void* d_ws, size_t ws_size,
                              hipStream_t stream) {
    const float* img    = (const float*)d_in[0];
    const float* knn    = (const float*)d_in[1];
    const float* pts    = (const float*)d_in[2];
    const float* f2d    = (const float*)d_in[3];
    const float* sift_W = (const float*)d_in[4];
    const float* sift_b = (const float*)d_in[5];
    const float* sift_g = (const float*)d_in[6];
    const float* sift_bt= (const float*)d_in[7];
    const float* c2_W1  = (const float*)d_in[8];
    const float* c2_b1  = (const float*)d_in[9];
    const float* c2_g1  = (const float*)d_in[10];
    const float* c2_bt1 = (const float*)d_in[11];
    const float* c2_W2  = (const float*)d_in[12];
    const float* c2_b2  = (const float*)d_in[13];
    const float* c2_g2  = (const float*)d_in[14];
    const float* c2_bt2 = (const float*)d_in[15];
    const float* lin1_W = (const float*)d_in[16];
    const float* lin1_b = (const float*)d_in[17];
    const float* c3_W1  = (const float*)d_in[18];
    const float* c3_b1  = (const float*)d_in[19];
    const float* c3_g1  = (const float*)d_in[20];
    const float* c3_bt1 = (const float*)d_in[21];
    const float* c3_W2  = (const float*)d_in[22];
    const float* c3_b2  = (const float*)d_in[23];
    const float* c3_g2  = (const float*)d_in[24];
    const float* c3_bt2 = (const float*)d_in[25];
    const float* pn2_W  = (const float*)d_in[26];
    const float* pn2_b  = (const float*)d_in[27];
    const float* pn2_g  = (const float*)d_in[28];
    const float* pn2_bt = (const float*)d_in[29];
    const float* fw1    = (const float*)d_in[30];
    const float* fw2    = (const float*)d_in[31];
    const float* fw3    = (const float*)d_in[32];

    float* ws  = (float*)d_ws;
    float* out = (float*)d_out;

    auto prep = [&](const float* W, const float* bb, const float* g, const float* bt,
                    int in_c, int out_c, int off_wt, int off_b, int has_bn) {
        int total = in_c * out_c;
        prep_weights<<<(total + 255) / 256, 256, 0, stream>>>(
            W, bb, g, bt, ws + off_wt, ws + off_b, in_c, out_c, has_bn);
    };
    prep(sift_W, sift_b, sift_g, sift_bt, 195, 128, OFF_W1T,  OFF_B1,  1);
    prep(c2_W1,  c2_b1,  c2_g1,  c2_bt1,  128,  64, OFF_W2AT, OFF_B2A, 1);
    prep(c2_W2,  c2_b2,  c2_g2,  c2_bt2,   64,  64, OFF_W2BT, OFF_B2B, 1);
    prep(lin1_W, lin1_b, lin1_b, lin1_b,   64,  64, OFF_LINT, OFF_LINB, 0);
    prep(c3_W1,  c3_b1,  c3_g1,  c3_bt1,  128,  64, OFF_W3AT, OFF_B3A, 1);
    prep(c3_W2,  c3_b2,  c3_g2,  c3_bt2,   64,  64, OFF_W3BT, OFF_B3B, 1);
    prep(pn2_W,  pn2_b,  pn2_g,  pn2_bt,   67, 128, OFF_PNT,  OFF_BPN, 1);

    fused_mvp<<<8192, 256, 0, stream>>>(img, knn, pts, f2d, fw1, fw2, fw3, ws, out);
}

// Round 2
// 336.678 us; speedup vs baseline: 1.3591x; 1.3591x over previous
//
#include <hip/hip_runtime.h>
#include <math.h>

#define N_PTS 8192
#define BATCH 4

// ws float offsets — BN-folded weights, row-major [out][in_pad], zero-padded cols
#define OFF_W1   0        // [128][196]
#define OFF_B1   25088    // [128]
#define OFF_W2A  25216    // [64][128]
#define OFF_B2A  33408    // [64]
#define OFF_W2B  33472    // [64][64]
#define OFF_B2B  37568    // [64]
#define OFF_LIN  37632    // [64][64]
#define OFF_LINB 41728    // [64]
#define OFF_W3A  41792    // [64][128]
#define OFF_B3A  49984    // [64]
#define OFF_W3B  50048    // [64][64]
#define OFF_B3B  54144    // [64]
#define OFF_PN   54208    // [128][68]
#define OFF_BPN  62912    // [128]
#define OFF_GEO  63040    // [4*8192]
// total 95808 floats = 383 KB

// output float offsets
#define OUT_SIM     0
#define OUT_DEEPSIM 32768
#define OUT_SHAL    65536
#define OUT_DEEP    (65536 + 2097152)

__global__ void prep_weights(const float* __restrict__ W, const float* __restrict__ b,
                             const float* __restrict__ g, const float* __restrict__ bt,
                             float* __restrict__ WT, float* __restrict__ bout,
                             int in_c, int in_pad, int out_c, int has_bn) {
    int t = blockIdx.x * 256 + threadIdx.x;
    int total = out_c * in_pad;
    if (t < total) {
        int o = t / in_pad, c = t % in_pad;
        float v = 0.0f;
        if (c < in_c) v = W[o * in_c + c] * (has_bn ? g[o] : 1.0f);
        WT[t] = v;
    }
    if (t < out_c) bout[t] = has_bn ? fmaf(g[t], b[t], bt[t]) : b[t];
}

// ---- kernel 1: min pairwise distance -> geo factor -------------------------
__global__ __launch_bounds__(256)
void dist_kernel(const float* __restrict__ img, const float* __restrict__ knn,
                 const float* __restrict__ fw1p, const float* __restrict__ fw2p,
                 float* __restrict__ geo_out) {
    __shared__ float4 if4s[4][64];
    const int tid = threadIdx.x, wid = tid >> 6, lane = tid & 63;
    const int p = blockIdx.x * 4 + wid;
    const int b = p >> 13, n = p & (N_PTS - 1);

    size_t imgBase = ((size_t)(b * 3) * N_PTS + n) * 64;
    float ix = img[imgBase + lane];
    float iy = img[imgBase + (size_t)N_PTS * 64 + lane];
    float iz = img[imgBase + 2 * (size_t)N_PTS * 64 + lane];
    size_t knnBase = (size_t)(b * 3) * 64 * N_PTS + n;
    float rx = knn[knnBase + (size_t)lane * N_PTS];
    float ry = knn[knnBase + (size_t)(64 + lane) * N_PTS];
    float rz = knn[knnBase + (size_t)(128 + lane) * N_PTS];

    if4s[wid][lane] = make_float4(ix, iy, iz, ix * ix + iy * iy + iz * iz);
    float r2 = rx * rx + ry * ry + rz * rz;
    __syncthreads();

    float dmin = 3.0e38f;
    #pragma unroll 8
    for (int l = 0; l < 64; ++l) {
        float4 v = if4s[wid][l];
        float cr = fmaf(rx, v.x, fmaf(ry, v.y, rz * v.z));
        dmin = fminf(dmin, r2 + v.w - 2.0f * cr);
    }
    for (int off = 32; off > 0; off >>= 1)
        dmin = fminf(dmin, __shfl_xor(dmin, off, 64));
    if (lane == 0)
        geo_out[(size_t)b * N_PTS + n] = expf(-(1.0f / fw1p[0]) * dmin) + fw2p[0];
}

// ---- tiled layer: 8 outputs per wave-pass, scalar-broadcast weights --------
template<int INP>
__device__ __forceinline__ void layer8(const float* __restrict__ W,
                                       const float* __restrict__ bias, int o0,
                                       const float (* __restrict__ IN)[64], int lane,
                                       float acc[8]) {
    #pragma unroll
    for (int i = 0; i < 8; ++i) acc[i] = bias[o0 + i];
    #pragma unroll 2
    for (int c4 = 0; c4 < INP / 4; ++c4) {
        float x0 = IN[4 * c4 + 0][lane];
        float x1 = IN[4 * c4 + 1][lane];
        float x2 = IN[4 * c4 + 2][lane];
        float x3 = IN[4 * c4 + 3][lane];
        #pragma unroll
        for (int i = 0; i < 8; ++i) {
            const float4 w = *(const float4*)(W + (o0 + i) * INP + 4 * c4);
            acc[i] = fmaf(w.w, x3, fmaf(w.z, x2, fmaf(w.y, x1, fmaf(w.x, x0, acc[i]))));
        }
    }
}

// ---- kernel 2: full MLP chain, 64 points per block -------------------------
__global__ __launch_bounds__(512, 1)
void mlp_kernel(const float* __restrict__ img, const float* __restrict__ knn,
                const float* __restrict__ pts, const float* __restrict__ f2d,
                const float* __restrict__ ws, const float* __restrict__ fw3p,
                float* __restrict__ out) {
    __shared__ float X[196][64];
    __shared__ float Y[128][64];
    __shared__ float S[64][64];
    __shared__ float YR[64][64];
    __shared__ float RN[8][64], RR[8][64], RI[8][64];

    const int tid  = threadIdx.x;
    const int wid  = __builtin_amdgcn_readfirstlane(tid >> 6);
    const int lane = tid & 63;
    const int b    = blockIdx.x >> 7;
    const int n0   = (blockIdx.x & 127) << 6;
    const int n    = n0 + lane;

    const float* W1  = ws + OFF_W1;  const float* B1   = ws + OFF_B1;
    const float* W2A = ws + OFF_W2A; const float* B2A  = ws + OFF_B2A;
    const float* W2B = ws + OFF_W2B; const float* B2B  = ws + OFF_B2B;
    const float* LIN = ws + OFF_LIN; const float* LINB = ws + OFF_LINB;
    const float* W3A = ws + OFF_W3A; const float* B3A  = ws + OFF_B3A;
    const float* W3B = ws + OFF_W3B; const float* B3B  = ws + OFF_B3B;
    const float* PN  = ws + OFF_PN;  const float* BPN  = ws + OFF_BPN;

    float acc[8], srv[8], siv[8];

    // ---- stage real rep: rows 0..2 points, 3..194 knn, row 195 zero pad ----
    if (wid == 0) X[195][lane] = 0.0f;
    for (int ch = wid; ch < 3; ch += 8)
        X[ch][lane] = pts[(size_t)(b * 3 + ch) * N_PTS + n];
    for (int ch = wid; ch < 192; ch += 8) {
        int c = ch >> 6, k = ch & 63;
        X[3 + ch][lane] = knn[((size_t)(b * 3 + c) * 64 + k) * N_PTS + n];
    }
    __syncthreads();

    // ---- real chain ----
    for (int pass = 0; pass < 2; ++pass) {
        int o0 = wid * 16 + pass * 8;
        layer8<196>(W1, B1, o0, X, lane, acc);
        #pragma unroll
        for (int i = 0; i < 8; ++i) Y[o0 + i][lane] = fmaxf(acc[i], 0.0f);
    }
    __syncthreads();
    {
        int o0 = wid * 8;
        layer8<128>(W2A, B2A, o0, Y, lane, acc);
        #pragma unroll
        for (int i = 0; i < 8; ++i) S[o0 + i][lane] = fmaxf(acc[i], 0.0f);
    }
    __syncthreads();
    {
        int o0 = wid * 8;
        layer8<64>(W2B, B2B, o0, S, lane, acc);
        #pragma unroll
        for (int i = 0; i < 8; ++i) {
            float v = fmaxf(acc[i], 0.0f);
            YR[o0 + i][lane] = v;
            out[OUT_SHAL + (size_t)(b * 64 + o0 + i) * N_PTS + n] = v;
        }
    }
    __syncthreads();
    layer8<64>(LIN, LINB, wid * 8, YR, lane, srv);

    // ---- stage image rep (rows 3..194; points rows persist) ----
    for (int c = 0; c < 3; ++c)
        for (int k4 = wid; k4 < 16; k4 += 8) {
            float4 v = *(const float4*)&img[(((size_t)(b * 3 + c)) * N_PTS + n) * 64 + k4 * 4];
            X[3 + c * 64 + k4 * 4 + 0][lane] = v.x;
            X[3 + c * 64 + k4 * 4 + 1][lane] = v.y;
            X[3 + c * 64 + k4 * 4 + 2][lane] = v.z;
            X[3 + c * 64 + k4 * 4 + 3][lane] = v.w;
        }
    __syncthreads();

    // ---- image chain ----
    for (int pass = 0; pass < 2; ++pass) {
        int o0 = wid * 16 + pass * 8;
        layer8<196>(W1, B1, o0, X, lane, acc);
        #pragma unroll
        for (int i = 0; i < 8; ++i) Y[o0 + i][lane] = fmaxf(acc[i], 0.0f);
    }
    __syncthreads();
    {
        int o0 = wid * 8;
        layer8<128>(W2A, B2A, o0, Y, lane, acc);
        #pragma unroll
        for (int i = 0; i < 8; ++i) S[o0 + i][lane] = fmaxf(acc[i], 0.0f);
    }
    __syncthreads();
    {
        int o0 = wid * 8;
        layer8<64>(W2B, B2B, o0, S, lane, acc);
        #pragma unroll
        for (int i = 0; i < 8; ++i) Y[o0 + i][lane] = fmaxf(acc[i], 0.0f);  // image feat -> Y[0..63]
    }
    __syncthreads();
    layer8<64>(LIN, LINB, wid * 8, Y, lane, siv);

    // ---- cosine similarity ----
    float pn = 0.0f, pr = 0.0f, pi = 0.0f;
    #pragma unroll
    for (int i = 0; i < 8; ++i) {
        pn += srv[i] * siv[i];
        pr += srv[i] * srv[i];
        pi += siv[i] * siv[i];
    }
    RN[wid][lane] = pn; RR[wid][lane] = pr; RI[wid][lane] = pi;
    __syncthreads();
    float num = 0.0f, rr = 0.0f, ii = 0.0f;
    #pragma unroll
    for (int w = 0; w < 8; ++w) { num += RN[w][lane]; rr += RR[w][lane]; ii += RI[w][lane]; }
    float den = fmaxf(sqrtf(rr) * sqrtf(ii), 1e-8f);
    float geo = ws[OFF_GEO + (size_t)b * N_PTS + n];
    float sim = num / den * geo;
    if (wid == 0) {
        out[OUT_SIM     + (size_t)b * N_PTS + n] = sim;
        out[OUT_DEEPSIM + (size_t)b * N_PTS + n] = fw3p[0];
    }

    // ---- fused = [shallowrealfeat ; sim * f2d] into Y ----
    for (int ch = wid; ch < 64; ch += 8) {
        Y[ch][lane]      = YR[ch][lane];
        Y[64 + ch][lane] = sim * f2d[(size_t)(b * 64 + ch) * N_PTS + n];
    }
    __syncthreads();
    {
        int o0 = wid * 8;
        layer8<128>(W3A, B3A, o0, Y, lane, acc);
        #pragma unroll
        for (int i = 0; i < 8; ++i) S[o0 + i][lane] = fmaxf(acc[i], 0.0f);
    }
    __syncthreads();
    {
        int o0 = wid * 8;
        layer8<64>(W3B, B3B, o0, S, lane, acc);
        #pragma unroll
        for (int i = 0; i < 8; ++i) X[3 + o0 + i][lane] = fmaxf(acc[i], 0.0f);
    }
    if (wid == 0) X[67][lane] = 0.0f;   // pad row (PN col 67 is zero anyway)
    __syncthreads();

    // ---- pn2: 68 -> 128, straight to global ----
    for (int pass = 0; pass < 2; ++pass) {
        int o0 = wid * 16 + pass * 8;
        layer8<68>(PN, BPN, o0, X, lane, acc);
        #pragma unroll
        for (int i = 0; i < 8; ++i)
            out[OUT_DEEP + (size_t)(b * 128 + o0 + i) * N_PTS + n] = fmaxf(acc[i], 0.0f);
    }
}

extern "C" void kernel_launch(void* const* d_in, const int* in_sizes, int n_in,
                              void* d_out, int out_size, void* d_ws, size_t ws_size,
                              hipStream_t stream) {
    const float* img    = (const float*)d_in[0];
    const float* knn    = (const float*)d_in[1];
    const float* pts    = (const float*)d_in[2];
    const float* f2d    = (const float*)d_in[3];
    const float* sift_W = (const float*)d_in[4];
    const float* sift_b = (const float*)d_in[5];
    const float* sift_g = (const float*)d_in[6];
    const float* sift_bt= (const float*)d_in[7];
    const float* c2_W1  = (const float*)d_in[8];
    const float* c2_b1  = (const float*)d_in[9];
    const float* c2_g1  = (const float*)d_in[10];
    const float* c2_bt1 = (const float*)d_in[11];
    const float* c2_W2  = (const float*)d_in[12];
    const float* c2_b2  = (const float*)d_in[13];
    const float* c2_g2  = (const float*)d_in[14];
    const float* c2_bt2 = (const float*)d_in[15];
    const float* lin1_W = (const float*)d_in[16];
    const float* lin1_b = (const float*)d_in[17];
    const float* c3_W1  = (const float*)d_in[18];
    const float* c3_b1  = (const float*)d_in[19];
    const float* c3_g1  = (const float*)d_in[20];
    const float* c3_bt1 = (const float*)d_in[21];
    const float* c3_W2  = (const float*)d_in[22];
    const float* c3_b2  = (const float*)d_in[23];
    const float* c3_g2  = (const float*)d_in[24];
    const float* c3_bt2 = (const float*)d_in[25];
    const float* pn2_W  = (const float*)d_in[26];
    const float* pn2_b  = (const float*)d_in[27];
    const float* pn2_g  = (const float*)d_in[28];
    const float* pn2_bt = (const float*)d_in[29];
    const float* fw1    = (const float*)d_in[30];
    const float* fw2    = (const float*)d_in[31];
    const float* fw3    = (const float*)d_in[32];

    float* ws  = (float*)d_ws;
    float* out = (float*)d_out;

    auto prep = [&](const float* W, const float* bb, const float* g, const float* bt,
                    int in_c, int in_pad, int out_c, int off_w, int off_b, int has_bn) {
        int total = out_c * in_pad;
        prep_weights<<<(total + 255) / 256, 256, 0, stream>>>(
            W, bb, g, bt, ws + off_w, ws + off_b, in_c, in_pad, out_c, has_bn);
    };
    prep(sift_W, sift_b, sift_g, sift_bt, 195, 196, 128, OFF_W1,  OFF_B1,  1);
    prep(c2_W1,  c2_b1,  c2_g1,  c2_bt1,  128, 128,  64, OFF_W2A, OFF_B2A, 1);
    prep(c2_W2,  c2_b2,  c2_g2,  c2_bt2,   64,  64,  64, OFF_W2B, OFF_B2B, 1);
    prep(lin1_W, lin1_b, lin1_b, lin1_b,   64,  64,  64, OFF_LIN, OFF_LINB, 0);
    prep(c3_W1,  c3_b1,  c3_g1,  c3_bt1,  128, 128,  64, OFF_W3A, OFF_B3A, 1);
    prep(c3_W2,  c3_b2,  c3_g2,  c3_bt2,   64,  64,  64, OFF_W3B, OFF_B3B, 1);
    prep(pn2_W,  pn2_b,  pn2_g,  pn2_bt,   67,  68, 128, OFF_PN,  OFF_BPN, 1);

    dist_kernel<<<8192, 256, 0, stream>>>(img, knn, fw1, fw2, ws + OFF_GEO);
    mlp_kernel<<<512, 512, 0, stream>>>(img, knn, pts, f2d, ws, fw3, out);
}

// Round 3
// 130.111 us; speedup vs baseline: 3.5169x; 2.5876x over previous
//
#include <hip/hip_runtime.h>
#include <math.h>

typedef __attribute__((ext_vector_type(8))) short short8;
typedef __attribute__((ext_vector_type(4))) float f32x4;
typedef unsigned short ushort_t;

#define N_PTS 8192

// packed-weight offsets in ws (ushort units), fragment order [(mt*KS+ks)*64+lane][8]
#define WP1   0       // MT8 KS7 -> 28672
#define WP2A  28672   // MT4 KS5 -> 10240
#define WP2B  38912   // MT4 KS3 -> 6144
#define WLIN  45056   // MT4 KS3 -> 6144
#define WC3A  51200   // MT4 KS5 -> 10240
#define WC3B  61440   // MT4 KS3 -> 6144
#define WPN   67584   // MT8 KS3 -> 12288  (end 79872)

// output float offsets
#define OUT_SIM  0
#define OUT_DSIM 32768
#define OUT_SHAL 65536
#define OUT_DEEP 2162688   // 65536 + 4*64*8192

// LDS carve (ushort units)
#define S_X1  0        // [64][232]  K=224 inputs (img then real)
#define S_X2  14848    // [64][168]  K=160 (L1 out + bias)
#define S_X3A 25600    // [64][104]  K=96
#define S_X3B 32256    // [64][104]  K=96
#define S_IV  14848    // ivec overlay on X2..X3A: 4096*4 ushort
#define S_X4  0        // deep_in overlay on X1: [64][104]
#define S_F2  6656     // sim*f2d overlay on X1: [64][104]

__device__ __forceinline__ ushort_t f2bf(float x) {
    unsigned u = __float_as_uint(x);
    return (ushort_t)((u + 0x7FFFu + ((u >> 16) & 1u)) >> 16);
}
__device__ __forceinline__ float bf2f(ushort_t h) {
    return __uint_as_float(((unsigned)h) << 16);
}

// ---- weight pack: fragment-order bf16, BN-folded, bias as extra channel ----
__global__ void prep_pack(const float* __restrict__ W, const float* __restrict__ b,
                          const float* __restrict__ g, const float* __restrict__ bt,
                          ushort_t* __restrict__ WP, int in_c, int MT, int KS,
                          int mode, int has_bn) {
    int t = blockIdx.x * 256 + threadIdx.x;
    int total = MT * KS * 64;
    if (t >= total) return;
    int lane = t & 63, u = t >> 6, ks = u % KS, mt = u / KS;
    int m  = mt * 16 + (lane & 15);
    int k0 = ks * 32 + ((lane >> 4) << 3);
    float scale = has_bn ? g[m] : 1.0f;
    float bias  = has_bn ? fmaf(g[m], b[m], bt[m]) : b[m];
    ushort_t o[8];
    #pragma unroll
    for (int i = 0; i < 8; ++i) {
        int k = k0 + i; float v = 0.0f;
        if (mode == 1) {          // L1: logical k = [repre 0..191 ; pts 192..194 ; bias 195]
            if (k < 192)      v = W[m * 195 + 3 + k] * scale;
            else if (k < 195) v = W[m * 195 + (k - 192)] * scale;
            else if (k == 195) v = bias;
        } else if (mode == 2) {   // PN2: logical k = [fused 0..63 ; pts 64..66 ; bias 67]
            if (k < 64)       v = W[m * 67 + 3 + k] * scale;
            else if (k < 67)  v = W[m * 67 + (k - 64)] * scale;
            else if (k == 67) v = bias;
        } else {                  // identity + bias@in_c
            if (k < in_c)       v = W[m * in_c + k] * scale;
            else if (k == in_c) v = bias;
        }
        o[i] = f2bf(v);
    }
    ushort4 lo, hi;
    lo.x = o[0]; lo.y = o[1]; lo.z = o[2]; lo.w = o[3];
    hi.x = o[4]; hi.y = o[5]; hi.z = o[6]; hi.w = o[7];
    *(ushort4*)(WP + t * 8)     = lo;
    *(ushort4*)(WP + t * 8 + 4) = hi;
}

template<int KS, int NTS>
__device__ __forceinline__ void mfma_tiles(const short8* __restrict__ WP, int mt, int nt0,
                                           const ushort_t* __restrict__ Xin, int sin,
                                           int lane, f32x4 acc[NTS]) {
    #pragma unroll
    for (int t = 0; t < NTS; ++t) acc[t] = (f32x4){0.f, 0.f, 0.f, 0.f};
    #pragma unroll
    for (int ks = 0; ks < KS; ++ks) {
        short8 a = WP[(mt * KS + ks) * 64 + lane];
        #pragma unroll
        for (int t = 0; t < NTS; ++t) {
            const short8 bv = *(const short8*)(Xin + ((lane & 15) + (nt0 + t) * 16) * sin
                                               + ks * 32 + ((lane >> 4) << 3));
            acc[t] = __builtin_amdgcn_mfma_f32_16x16x32_bf16(a, bv, acc[t], 0, 0, 0);
        }
    }
}

template<int NTS>
__device__ __forceinline__ void epi_relu_lds(const f32x4 acc[NTS], int mt, int nt0,
                                             int h, int p, ushort_t* Xout, int sout) {
    int ch0 = mt * 16 + h * 4;
    #pragma unroll
    for (int t = 0; t < NTS; ++t) {
        int pt = p + (nt0 + t) * 16;
        ushort4 u;
        u.x = f2bf(fmaxf(acc[t].x, 0.f)); u.y = f2bf(fmaxf(acc[t].y, 0.f));
        u.z = f2bf(fmaxf(acc[t].z, 0.f)); u.w = f2bf(fmaxf(acc[t].w, 0.f));
        *(ushort4*)(Xout + pt * sout + ch0) = u;
    }
}

__global__ __launch_bounds__(512, 4)
void fused_all(const float* __restrict__ img,   // [4][3][8192][64]
               const float* __restrict__ knn,   // [4][3][64][8192]
               const float* __restrict__ pts,   // [4][3][8192]
               const float* __restrict__ f2d,   // [4][64][8192]
               const float* __restrict__ fw1p, const float* __restrict__ fw2p,
               const float* __restrict__ fw3p,
               const ushort_t* __restrict__ wsp, float* __restrict__ out)
{
    __shared__ ushort_t SMEM[38912];
    __shared__ float DMIN[64];
    __shared__ float SIMB[64];
    __shared__ float RBUF[3][8][2][16];

    const int tid  = threadIdx.x;
    const int wid  = __builtin_amdgcn_readfirstlane(tid >> 6);
    const int lane = tid & 63;
    const int p16  = lane & 15;
    const int h    = lane >> 4;
    const int b    = blockIdx.x >> 7;
    const int n0   = (blockIdx.x & 127) << 6;

    const int mt64  = wid & 3;
    const int nt064 = (wid >> 2) * 2;

    f32x4 siv[2], srv[2], a4[4], a2[2];

    // ================= step 1: init pads + stage IMAGE into X1 =============
    for (int e = tid; e < 64 * 29; e += 512) {          // X1 ch195 bias, 196..223 zero
        int pt = e / 29, c = 195 + e % 29;
        SMEM[S_X1 + pt * 232 + c] = (c == 195) ? 0x3F80 : 0;
    }
    for (int e = tid; e < 64 * 32; e += 512) {          // X2 ch128 bias, 129..159 zero
        int pt = e >> 5, c = 128 + (e & 31);
        SMEM[S_X2 + pt * 168 + c] = (c == 128) ? 0x3F80 : 0;
    }
    for (int e = tid; e < 64 * 32; e += 512) {          // X3A/X3B ch64 bias, 65..95 zero
        int pt = e >> 5, c = 64 + (e & 31);
        ushort_t v = (c == 64) ? 0x3F80 : 0;
        SMEM[S_X3A + pt * 104 + c] = v;
        SMEM[S_X3B + pt * 104 + c] = v;
    }
    {   // img channels 0..191 (ch = c*64 + k)
        int pt = tid >> 3, q = tid & 7;
        #pragma unroll
        for (int c = 0; c < 3; ++c) {
            const float4* gp = (const float4*)(img + (((size_t)(b * 3 + c) * N_PTS) + n0 + pt) * 64 + q * 8);
            float4 v0 = gp[0], v1 = gp[1];
            ushort4 lo, hi;
            lo.x = f2bf(v0.x); lo.y = f2bf(v0.y); lo.z = f2bf(v0.z); lo.w = f2bf(v0.w);
            hi.x = f2bf(v1.x); hi.y = f2bf(v1.y); hi.z = f2bf(v1.z); hi.w = f2bf(v1.w);
            ushort_t* dst = SMEM + S_X1 + pt * 232 + c * 64 + q * 8;
            *(ushort4*)dst = lo;
            *(ushort4*)(dst + 4) = hi;
        }
    }
    if (tid < 192) {                                     // pts ch 192..194
        int c = tid >> 6, pt = tid & 63;
        SMEM[S_X1 + pt * 232 + 192 + c] = f2bf(pts[((size_t)(b * 3 + c)) * N_PTS + n0 + pt]);
    }
    __syncthreads();

    // ================= image chain =========================================
    mfma_tiles<7, 4>((const short8*)(wsp + WP1), wid, 0, SMEM + S_X1, 232, lane, a4);
    epi_relu_lds<4>(a4, wid, 0, h, p16, SMEM + S_X2, 168);
    __syncthreads();

    mfma_tiles<5, 2>((const short8*)(wsp + WP2A), mt64, nt064, SMEM + S_X2, 168, lane, a2);
    epi_relu_lds<2>(a2, mt64, nt064, h, p16, SMEM + S_X3A, 104);
    __syncthreads();

    mfma_tiles<3, 2>((const short8*)(wsp + WP2B), mt64, nt064, SMEM + S_X3A, 104, lane, a2);
    epi_relu_lds<2>(a2, mt64, nt064, h, p16, SMEM + S_X3B, 104);
    __syncthreads();

    mfma_tiles<3, 2>((const short8*)(wsp + WLIN), mt64, nt064, SMEM + S_X3B, 104, lane, siv);
    // copy image coords -> compact ivec (overlay X2..X3A)
    for (int e = tid; e < 4096; e += 512) {
        int pt = e >> 6, l = e & 63;
        ushort4 v;
        v.x = SMEM[S_X1 + pt * 232 + l];
        v.y = SMEM[S_X1 + pt * 232 + 64 + l];
        v.z = SMEM[S_X1 + pt * 232 + 128 + l];
        v.w = 0;
        *(ushort4*)(SMEM + S_IV + e * 4) = v;
    }
    __syncthreads();

    // ================= stage REAL (knn) into X1 ch0..191 ===================
    {
        int w8 = tid >> 6, pt = tid & 63;
        #pragma unroll
        for (int j = 0; j < 24; ++j) {
            int ch = j * 8 + w8;
            float v = knn[((size_t)(b * 3 + (ch >> 6)) * 64 + (ch & 63)) * N_PTS + n0 + pt];
            SMEM[S_X1 + pt * 232 + ch] = f2bf(v);
        }
    }
    __syncthreads();

    // ================= dist: min pairwise sq-dist per point ================
    #pragma unroll 2
    for (int j = 0; j < 8; ++j) {
        int pt = wid * 8 + j;
        float rx = bf2f(SMEM[S_X1 + pt * 232 + lane]);
        float ry = bf2f(SMEM[S_X1 + pt * 232 + 64 + lane]);
        float rz = bf2f(SMEM[S_X1 + pt * 232 + 128 + lane]);
        float r2 = fmaf(rx, rx, fmaf(ry, ry, rz * rz));
        float dmin = 3.0e38f;
        #pragma unroll 8
        for (int l = 0; l < 64; ++l) {
            uint2 v = *(const uint2*)(SMEM + S_IV + (pt * 64 + l) * 4);
            float fx = __uint_as_float(v.x << 16);
            float fy = __uint_as_float(v.x & 0xFFFF0000u);
            float fz = __uint_as_float(v.y << 16);
            float i2 = fmaf(fx, fx, fmaf(fy, fy, fz * fz));
            float cr = fmaf(rx, fx, fmaf(ry, fy, rz * fz));
            dmin = fminf(dmin, (r2 + i2) - 2.0f * cr);
        }
        #pragma unroll
        for (int off = 32; off > 0; off >>= 1)
            dmin = fminf(dmin, __shfl_xor(dmin, off, 64));
        if (lane == 0) DMIN[pt] = dmin;
    }
    __syncthreads();

    // ================= real chain ==========================================
    mfma_tiles<7, 4>((const short8*)(wsp + WP1), wid, 0, SMEM + S_X1, 232, lane, a4);
    epi_relu_lds<4>(a4, wid, 0, h, p16, SMEM + S_X2, 168);
    for (int e = tid; e < 64 * 32; e += 512) {          // re-init X2 bias/pads (ivec clobbered)
        int pt = e >> 5, c = 128 + (e & 31);
        SMEM[S_X2 + pt * 168 + c] = (c == 128) ? 0x3F80 : 0;
    }
    __syncthreads();

    mfma_tiles<5, 2>((const short8*)(wsp + WP2A), mt64, nt064, SMEM + S_X2, 168, lane, a2);
    epi_relu_lds<2>(a2, mt64, nt064, h, p16, SMEM + S_X3A, 104);
    for (int e = tid; e < 64 * 32; e += 512) {          // re-init X3A bias/pads
        int pt = e >> 5, c = 64 + (e & 31);
        SMEM[S_X3A + pt * 104 + c] = (c == 64) ? 0x3F80 : 0;
    }
    __syncthreads();

    // L2B real: LDS + global shallowrealfeat
    mfma_tiles<3, 2>((const short8*)(wsp + WP2B), mt64, nt064, SMEM + S_X3A, 104, lane, a2);
    {
        int ch0 = mt64 * 16 + h * 4;
        #pragma unroll
        for (int t = 0; t < 2; ++t) {
            int pt = p16 + (nt064 + t) * 16;
            float vv[4] = {fmaxf(a2[t].x, 0.f), fmaxf(a2[t].y, 0.f),
                           fmaxf(a2[t].z, 0.f), fmaxf(a2[t].w, 0.f)};
            ushort4 u;
            u.x = f2bf(vv[0]); u.y = f2bf(vv[1]); u.z = f2bf(vv[2]); u.w = f2bf(vv[3]);
            *(ushort4*)(SMEM + S_X3B + pt * 104 + ch0) = u;
            #pragma unroll
            for (int r = 0; r < 4; ++r)
                out[OUT_SHAL + ((size_t)(b * 64 + ch0 + r)) * N_PTS + n0 + pt] = vv[r];
        }
    }
    __syncthreads();

    mfma_tiles<3, 2>((const short8*)(wsp + WLIN), mt64, nt064, SMEM + S_X3B, 104, lane, srv);
    {   // cosine partials -> RBUF
        #pragma unroll
        for (int t = 0; t < 2; ++t) {
            float pn = srv[t].x * siv[t].x + srv[t].y * siv[t].y + srv[t].z * siv[t].z + srv[t].w * siv[t].w;
            float pr = srv[t].x * srv[t].x + srv[t].y * srv[t].y + srv[t].z * srv[t].z + srv[t].w * srv[t].w;
            float pi = siv[t].x * siv[t].x + siv[t].y * siv[t].y + siv[t].z * siv[t].z + siv[t].w * siv[t].w;
            pn += __shfl_xor(pn, 16, 64); pn += __shfl_xor(pn, 32, 64);
            pr += __shfl_xor(pr, 16, 64); pr += __shfl_xor(pr, 32, 64);
            pi += __shfl_xor(pi, 16, 64); pi += __shfl_xor(pi, 32, 64);
            if (lane < 16) {
                RBUF[0][wid][t][lane] = pn;
                RBUF[1][wid][t][lane] = pr;
                RBUF[2][wid][t][lane] = pi;
            }
        }
    }
    __syncthreads();

    // ================= similarity ==========================================
    if (tid < 64) {
        int pt = tid, nt = pt >> 4, t = nt & 1, grp = nt >> 1, pp = pt & 15;
        float num = 0.f, rr = 0.f, ii = 0.f;
        #pragma unroll
        for (int m = 0; m < 4; ++m) {
            int w = grp * 4 + m;
            num += RBUF[0][w][t][pp]; rr += RBUF[1][w][t][pp]; ii += RBUF[2][w][t][pp];
        }
        float den = fmaxf(sqrtf(rr) * sqrtf(ii), 1e-8f);
        float geo = expf(-(1.0f / fw1p[0]) * DMIN[pt]) + fw2p[0];
        float sim = (num / den) * geo;
        SIMB[pt] = sim;
        out[OUT_SIM  + (size_t)b * N_PTS + n0 + pt] = sim;
        out[OUT_DSIM + (size_t)b * N_PTS + n0 + pt] = fw3p[0];
    }
    __syncthreads();

    // ================= F2 = sim * f2d (overlay on X1) ======================
    {
        int w8 = tid >> 6, pt = tid & 63;
        float s = SIMB[pt];
        #pragma unroll
        for (int j = 0; j < 8; ++j) {
            int ch = j * 8 + w8;
            float v = s * f2d[((size_t)(b * 64 + ch)) * N_PTS + n0 + pt];
            SMEM[S_F2 + pt * 104 + ch] = f2bf(v);
        }
        for (int e = tid; e < 64 * 32; e += 512) {
            int pt2 = e >> 5, c = 64 + (e & 31);
            SMEM[S_F2 + pt2 * 104 + c] = (c == 64) ? 0x3F80 : 0;
        }
    }
    __syncthreads();

    // ================= C3A: [shal(X3B) ; F2] -> X3A ========================
    {
        const short8* W = (const short8*)(wsp + WC3A);
        #pragma unroll
        for (int t = 0; t < 2; ++t) a2[t] = (f32x4){0.f, 0.f, 0.f, 0.f};
        #pragma unroll
        for (int ks = 0; ks < 5; ++ks) {
            short8 a = W[(mt64 * 5 + ks) * 64 + lane];
            #pragma unroll
            for (int t = 0; t < 2; ++t) {
                int row = (p16 + (nt064 + t) * 16) * 104 + ((lane >> 4) << 3);
                const ushort_t* src = (ks < 2)
                    ? (SMEM + S_X3B + row + ks * 32)
                    : (SMEM + S_F2  + row + (ks - 2) * 32);
                a2[t] = __builtin_amdgcn_mfma_f32_16x16x32_bf16(a, *(const short8*)src, a2[t], 0, 0, 0);
            }
        }
        epi_relu_lds<2>(a2, mt64, nt064, h, p16, SMEM + S_X3A, 104);
    }
    __syncthreads();

    // ================= X4 statics + C3B -> X4 ==============================
    if (tid < 192) {                                     // pts at ch 64..66
        int c = tid >> 6, pt = tid & 63;
        SMEM[S_X4 + pt * 104 + 64 + c] = f2bf(pts[((size_t)(b * 3 + c)) * N_PTS + n0 + pt]);
    }
    for (int e = tid; e < 64 * 29; e += 512) {           // bias@67, zeros 68..95
        int pt = e / 29, c = 67 + e % 29;
        SMEM[S_X4 + pt * 104 + c] = (c == 67) ? 0x3F80 : 0;
    }
    mfma_tiles<3, 2>((const short8*)(wsp + WC3B), mt64, nt064, SMEM + S_X3A, 104, lane, a2);
    epi_relu_lds<2>(a2, mt64, nt064, h, p16, SMEM + S_X4, 104);   // fused at ch 0..63
    __syncthreads();

    // ================= PN2: X4 -> deeprealfeat (global) ====================
    mfma_tiles<3, 4>((const short8*)(wsp + WPN), wid, 0, SMEM + S_X4, 104, lane, a4);
    {
        int ch0 = wid * 16 + h * 4;
        #pragma unroll
        for (int t = 0; t < 4; ++t) {
            int pt = p16 + t * 16;
            float vv[4] = {fmaxf(a4[t].x, 0.f), fmaxf(a4[t].y, 0.f),
                           fmaxf(a4[t].z, 0.f), fmaxf(a4[t].w, 0.f)};
            #pragma unroll
            for (int r = 0; r < 4; ++r)
                out[OUT_DEEP + ((size_t)(b * 128 + ch0 + r)) * N_PTS + n0 + pt] = vv[r];
        }
    }
}

extern "C" void kernel_launch(void* const* d_in, const int* in_sizes, int n_in,
                              void* d_out, int out_size, void* d_ws, size_t ws_size,
                              hipStream_t stream) {
    const float* img    = (const float*)d_in[0];
    const float* knn    = (const float*)d_in[1];
    const float* pts    = (const float*)d_in[2];
    const float* f2d    = (const float*)d_in[3];
    const float* sift_W = (const float*)d_in[4];
    const float* sift_b = (const float*)d_in[5];
    const float* sift_g = (const float*)d_in[6];
    const float* sift_bt= (const float*)d_in[7];
    const float* c2_W1  = (const float*)d_in[8];
    const float* c2_b1  = (const float*)d_in[9];
    const float* c2_g1  = (const float*)d_in[10];
    const float* c2_bt1 = (const float*)d_in[11];
    const float* c2_W2  = (const float*)d_in[12];
    const float* c2_b2  = (const float*)d_in[13];
    const float* c2_g2  = (const float*)d_in[14];
    const float* c2_bt2 = (const float*)d_in[15];
    const float* lin1_W = (const float*)d_in[16];
    const float* lin1_b = (const float*)d_in[17];
    const float* c3_W1  = (const float*)d_in[18];
    const float* c3_b1  = (const float*)d_in[19];
    const float* c3_g1  = (const float*)d_in[20];
    const float* c3_bt1 = (const float*)d_in[21];
    const float* c3_W2  = (const float*)d_in[22];
    const float* c3_b2  = (const float*)d_in[23];
    const float* c3_g2  = (const float*)d_in[24];
    const float* c3_bt2 = (const float*)d_in[25];
    const float* pn2_W  = (const float*)d_in[26];
    const float* pn2_b  = (const float*)d_in[27];
    const float* pn2_g  = (const float*)d_in[28];
    const float* pn2_bt = (const float*)d_in[29];
    const float* fw1    = (const float*)d_in[30];
    const float* fw2    = (const float*)d_in[31];
    const float* fw3    = (const float*)d_in[32];

    ushort_t* wsp = (ushort_t*)d_ws;
    float* out = (float*)d_out;

    auto prep = [&](const float* W, const float* bb, const float* g, const float* bt,
                    int off, int in_c, int MT, int KS, int mode, int has_bn) {
        int total = MT * KS * 64;
        prep_pack<<<(total + 255) / 256, 256, 0, stream>>>(
            W, bb, g, bt, wsp + off, in_c, MT, KS, mode, has_bn);
    };
    prep(sift_W, sift_b, sift_g, sift_bt, WP1, 195, 8, 7, 1, 1);
    prep(c2_W1,  c2_b1,  c2_g1,  c2_bt1, WP2A, 128, 4, 5, 0, 1);
    prep(c2_W2,  c2_b2,  c2_g2,  c2_bt2, WP2B,  64, 4, 3, 0, 1);
    prep(lin1_W, lin1_b, lin1_b, lin1_b, WLIN,  64, 4, 3, 0, 0);
    prep(c3_W1,  c3_b1,  c3_g1,  c3_bt1, WC3A, 128, 4, 5, 0, 1);
    prep(c3_W2,  c3_b2,  c3_g2,  c3_bt2, WC3B,  64, 4, 3, 0, 1);
    prep(pn2_W,  pn2_b,  pn2_g,  pn2_bt, WPN,   67, 8, 3, 2, 1);

    fused_all<<<512, 512, 0, stream>>>(img, knn, pts, f2d, fw1, fw2, fw3, wsp, out);
}

// Round 4
// 96.315 us; speedup vs baseline: 4.7509x; 1.3509x over previous
//
#include <hip/hip_runtime.h>
#include <math.h>

typedef __attribute__((ext_vector_type(8))) short short8;
typedef __attribute__((ext_vector_type(4))) float f32x4;
typedef unsigned short ushort_t;

#define N_PTS 8192

// packed-weight offsets in ws (ushort units), fragment order [(mt*KS+ks)*64+lane][8]
#define WP1   0       // MT8 KS7 -> 28672
#define WP2A  28672   // MT4 KS5 -> 10240
#define WP2B  38912   // MT4 KS3 -> 6144
#define WLIN  45056   // MT4 KS3 -> 6144
#define WC3A  51200   // MT4 KS5 -> 10240
#define WC3B  61440   // MT4 KS3 -> 6144
#define WPN   67584   // MT8 KS3 -> 12288  (end 79872)

// output float offsets
#define OUT_SIM  0
#define OUT_DSIM 32768
#define OUT_SHAL 65536
#define OUT_DEEP 2162688   // 65536 + 4*64*8192

// LDS carve (ushort units), 32 points per block
#define S_X1  0        // [32][232]  -> 7424
#define S_X2  7424     // [32][168]  -> end 12800
#define S_X3A 12800    // [32][104]  -> end 16128
#define S_X3B 16128    // [32][104]  -> end 19456
#define S_IVC 7424     // overlay X2+X3A: [32][64] ushort4 = 8192 (end 15616)
#define S_X4  0        // overlay X1: [32][104] -> 3328
#define S_F2  3328     // overlay X1: [32][104] -> 6656

__device__ __forceinline__ ushort_t f2bf(float x) {
    unsigned u = __float_as_uint(x);
    return (ushort_t)((u + 0x7FFFu + ((u >> 16) & 1u)) >> 16);
}
__device__ __forceinline__ float bf2f(ushort_t h) {
    return __uint_as_float(((unsigned)h) << 16);
}

// ---- weight pack: fragment-order bf16, BN-folded, bias as extra channel ----
__global__ void prep_pack(const float* __restrict__ W, const float* __restrict__ b,
                          const float* __restrict__ g, const float* __restrict__ bt,
                          ushort_t* __restrict__ WP, int in_c, int MT, int KS,
                          int mode, int has_bn) {
    int t = blockIdx.x * 256 + threadIdx.x;
    int total = MT * KS * 64;
    if (t >= total) return;
    int lane = t & 63, u = t >> 6, ks = u % KS, mt = u / KS;
    int m  = mt * 16 + (lane & 15);
    int k0 = ks * 32 + ((lane >> 4) << 3);
    float scale = has_bn ? g[m] : 1.0f;
    float bias  = has_bn ? fmaf(g[m], b[m], bt[m]) : b[m];
    ushort_t o[8];
    #pragma unroll
    for (int i = 0; i < 8; ++i) {
        int k = k0 + i; float v = 0.0f;
        if (mode == 1) {          // L1: k = [repre 0..191 ; pts 192..194 ; bias 195]
            if (k < 192)      v = W[m * 195 + 3 + k] * scale;
            else if (k < 195) v = W[m * 195 + (k - 192)] * scale;
            else if (k == 195) v = bias;
        } else if (mode == 2) {   // PN2: k = [fused 0..63 ; pts 64..66 ; bias 67]
            if (k < 64)       v = W[m * 67 + 3 + k] * scale;
            else if (k < 67)  v = W[m * 67 + (k - 64)] * scale;
            else if (k == 67) v = bias;
        } else {                  // identity + bias@in_c
            if (k < in_c)       v = W[m * in_c + k] * scale;
            else if (k == in_c) v = bias;
        }
        o[i] = f2bf(v);
    }
    ushort4 lo, hi;
    lo.x = o[0]; lo.y = o[1]; lo.z = o[2]; lo.w = o[3];
    hi.x = o[4]; hi.y = o[5]; hi.z = o[6]; hi.w = o[7];
    *(ushort4*)(WP + t * 8)     = lo;
    *(ushort4*)(WP + t * 8 + 4) = hi;
}

template<int KS, int NTS>
__device__ __forceinline__ void mfma_tiles(const short8* __restrict__ WP, int mt, int nt0,
                                           const ushort_t* __restrict__ Xin, int sin,
                                           int lane, f32x4 acc[NTS]) {
    #pragma unroll
    for (int t = 0; t < NTS; ++t) acc[t] = (f32x4){0.f, 0.f, 0.f, 0.f};
    #pragma unroll
    for (int ks = 0; ks < KS; ++ks) {
        short8 a = WP[(mt * KS + ks) * 64 + lane];
        #pragma unroll
        for (int t = 0; t < NTS; ++t) {
            const short8 bv = *(const short8*)(Xin + ((lane & 15) + (nt0 + t) * 16) * sin
                                               + ks * 32 + ((lane >> 4) << 3));
            acc[t] = __builtin_amdgcn_mfma_f32_16x16x32_bf16(a, bv, acc[t], 0, 0, 0);
        }
    }
}

template<int NTS>
__device__ __forceinline__ void epi_relu_lds(const f32x4 acc[NTS], int mt, int nt0,
                                             int h, int p, ushort_t* Xout, int sout) {
    int ch0 = mt * 16 + h * 4;
    #pragma unroll
    for (int t = 0; t < NTS; ++t) {
        int pt = p + (nt0 + t) * 16;
        ushort4 u;
        u.x = f2bf(fmaxf(acc[t].x, 0.f)); u.y = f2bf(fmaxf(acc[t].y, 0.f));
        u.z = f2bf(fmaxf(acc[t].z, 0.f)); u.w = f2bf(fmaxf(acc[t].w, 0.f));
        *(ushort4*)(Xout + pt * sout + ch0) = u;
    }
}

__global__ __launch_bounds__(512, 6)
void fused_all(const float* __restrict__ img,   // [4][3][8192][64]
               const float* __restrict__ knn,   // [4][3][64][8192]
               const float* __restrict__ pts,   // [4][3][8192]
               const float* __restrict__ f2d,   // [4][64][8192]
               const float* __restrict__ fw1p, const float* __restrict__ fw2p,
               const float* __restrict__ fw3p,
               const ushort_t* __restrict__ wsp, float* __restrict__ out)
{
    __shared__ ushort_t SMEM[19456];
    __shared__ float DMIN[32];
    __shared__ float SIMB[32];
    __shared__ float RBUF[3][8][16];

    const int tid  = threadIdx.x;
    const int wid  = __builtin_amdgcn_readfirstlane(tid >> 6);
    const int lane = tid & 63;
    const int p16  = lane & 15;
    const int h    = lane >> 4;
    const int b    = blockIdx.x >> 8;
    const int n0   = (blockIdx.x & 255) << 5;

    const int mt64 = wid & 3;
    const int nt1  = wid >> 2;

    f32x4 a2[2], a1[1], sivA[1], srvA[1];
    const short8 zero8 = {0, 0, 0, 0, 0, 0, 0, 0};

    // ================= phase 1: pads + stage IMAGE + pts ===================
    for (int e = tid; e < 32 * 29; e += 512) {           // X1 ch195 bias, 196..223 zero
        int pt = e / 29, c = 195 + e % 29;
        SMEM[S_X1 + pt * 232 + c] = (c == 195) ? 0x3F80 : 0;
    }
    for (int e = tid; e < 32 * 32; e += 512) {           // X2 ch128 bias, 129..159 zero
        int pt = e >> 5, c = 128 + (e & 31);
        SMEM[S_X2 + pt * 168 + c] = (c == 128) ? 0x3F80 : 0;
    }
    for (int e = tid; e < 32 * 32; e += 512) {           // X3A/X3B ch64 bias, 65..95 zero
        int pt = e >> 5, c = 64 + (e & 31);
        ushort_t v = (c == 64) ? 0x3F80 : 0;
        SMEM[S_X3A + pt * 104 + c] = v;
        SMEM[S_X3B + pt * 104 + c] = v;
    }
    {   // img channels 0..191 (ch = c*64 + k): 16 threads per point
        int pt = tid >> 4, q = tid & 15;
        #pragma unroll
        for (int c = 0; c < 3; ++c) {
            float4 v = *(const float4*)(img + (((size_t)(b * 3 + c) * N_PTS) + n0 + pt) * 64 + q * 4);
            ushort4 u;
            u.x = f2bf(v.x); u.y = f2bf(v.y); u.z = f2bf(v.z); u.w = f2bf(v.w);
            *(ushort4*)(SMEM + S_X1 + pt * 232 + c * 64 + q * 4) = u;
        }
    }
    if (tid < 96) {                                      // pts ch 192..194
        int c = tid >> 5, pt = tid & 31;
        SMEM[S_X1 + pt * 232 + 192 + c] = f2bf(pts[((size_t)(b * 3 + c)) * N_PTS + n0 + pt]);
    }
    __syncthreads();

    // ================= image chain =========================================
    mfma_tiles<7, 2>((const short8*)(wsp + WP1), wid, 0, SMEM + S_X1, 232, lane, a2);
    epi_relu_lds<2>(a2, wid, 0, h, p16, SMEM + S_X2, 168);
    __syncthreads();

    mfma_tiles<5, 1>((const short8*)(wsp + WP2A), mt64, nt1, SMEM + S_X2, 168, lane, a1);
    epi_relu_lds<1>(a1, mt64, nt1, h, p16, SMEM + S_X3A, 104);
    __syncthreads();

    mfma_tiles<3, 1>((const short8*)(wsp + WP2B), mt64, nt1, SMEM + S_X3A, 104, lane, a1);
    epi_relu_lds<1>(a1, mt64, nt1, h, p16, SMEM + S_X3B, 104);
    __syncthreads();

    // LIN(img) -> siv regs; build centered image coord table IVC (overlay X2/X3A)
    mfma_tiles<3, 1>((const short8*)(wsp + WLIN), mt64, nt1, SMEM + S_X3B, 104, lane, sivA);
    for (int e = tid; e < 32 * 64; e += 512) {
        int pt = e >> 6, l = e & 63;
        const ushort_t* row = SMEM + S_X1 + pt * 232;
        float ix = bf2f(row[l]), iy = bf2f(row[64 + l]), iz = bf2f(row[128 + l]);
        float px = bf2f(row[192]), py = bf2f(row[193]), pz = bf2f(row[194]);
        float fx = ix - px, fy = iy - py, fz = iz - pz;
        float i2 = fmaf(fx, fx, fmaf(fy, fy, fz * fz));
        ushort4 u;
        u.x = f2bf(fx); u.y = f2bf(fy); u.z = f2bf(fz); u.w = f2bf(i2);
        *(ushort4*)(SMEM + S_IVC + e * 4) = u;
    }
    __syncthreads();

    // ================= stage REAL (knn) into X1 ch0..191 ===================
    {
        int pt = tid & 31, gb = (tid >> 5) * 3;
        #pragma unroll
        for (int j = 0; j < 3; ++j) {
            int ch0 = (gb + j) * 4;
            int c3 = ch0 >> 6, k0 = ch0 & 63;
            const float* base = knn + ((size_t)(b * 3 + c3) * 64 + k0) * N_PTS + n0 + pt;
            ushort4 u;
            u.x = f2bf(base[0]);
            u.y = f2bf(base[(size_t)N_PTS]);
            u.z = f2bf(base[2 * (size_t)N_PTS]);
            u.w = f2bf(base[3 * (size_t)N_PTS]);
            *(ushort4*)(SMEM + S_X1 + pt * 232 + ch0) = u;
        }
    }
    __syncthreads();

    // ================= dist via MFMA (one wave = one point) ================
    #pragma unroll 1
    for (int j = 0; j < 4; ++j) {
        int pt = wid * 4 + j;
        const ushort_t* row = SMEM + S_X1 + pt * 232;
        float px = bf2f(row[192]), py = bf2f(row[193]), pz = bf2f(row[194]);
        f32x4 m4 = (f32x4){3.0e38f, 3.0e38f, 3.0e38f, 3.0e38f};
        #pragma unroll 1
        for (int kt = 0; kt < 4; ++kt) {
            int k = kt * 16 + p16;
            float rx = bf2f(row[k]) - px;
            float ry = bf2f(row[64 + k]) - py;
            float rz = bf2f(row[128 + k]) - pz;
            float r2 = fmaf(rx, rx, fmaf(ry, ry, rz * rz));
            short8 af = zero8;
            if (h == 0) {
                af[0] = (short)f2bf(-2.0f * rx);
                af[1] = (short)f2bf(-2.0f * ry);
                af[2] = (short)f2bf(-2.0f * rz);
                af[3] = (short)f2bf(r2);
                af[4] = (short)0x3F80;
            }
            #pragma unroll
            for (int lt = 0; lt < 4; ++lt) {
                ushort4 iv = *(const ushort4*)(SMEM + S_IVC + (pt * 64 + lt * 16 + p16) * 4);
                short8 bf = zero8;
                if (h == 0) {
                    bf[0] = (short)iv.x; bf[1] = (short)iv.y; bf[2] = (short)iv.z;
                    bf[3] = (short)0x3F80; bf[4] = (short)iv.w;
                }
                f32x4 acc = __builtin_amdgcn_mfma_f32_16x16x32_bf16(af, bf,
                                (f32x4){0.f, 0.f, 0.f, 0.f}, 0, 0, 0);
                m4.x = fminf(m4.x, acc.x); m4.y = fminf(m4.y, acc.y);
                m4.z = fminf(m4.z, acc.z); m4.w = fminf(m4.w, acc.w);
            }
        }
        float v = fminf(fminf(m4.x, m4.y), fminf(m4.z, m4.w));
        #pragma unroll
        for (int off = 32; off > 0; off >>= 1)
            v = fminf(v, __shfl_xor(v, off, 64));
        if (lane == 0) DMIN[pt] = v;
    }
    __syncthreads();

    // ================= real chain ==========================================
    mfma_tiles<7, 2>((const short8*)(wsp + WP1), wid, 0, SMEM + S_X1, 232, lane, a2);
    epi_relu_lds<2>(a2, wid, 0, h, p16, SMEM + S_X2, 168);
    for (int e = tid; e < 32 * 32; e += 512) {           // re-init X2 pads (IVC clobbered)
        int pt = e >> 5, c = 128 + (e & 31);
        SMEM[S_X2 + pt * 168 + c] = (c == 128) ? 0x3F80 : 0;
    }
    __syncthreads();

    mfma_tiles<5, 1>((const short8*)(wsp + WP2A), mt64, nt1, SMEM + S_X2, 168, lane, a1);
    epi_relu_lds<1>(a1, mt64, nt1, h, p16, SMEM + S_X3A, 104);
    for (int e = tid; e < 32 * 32; e += 512) {           // re-init X3A pads (IVC clobbered)
        int pt = e >> 5, c = 64 + (e & 31);
        SMEM[S_X3A + pt * 104 + c] = (c == 64) ? 0x3F80 : 0;
    }
    __syncthreads();

    // L2B real -> X3B + global shallowrealfeat
    mfma_tiles<3, 1>((const short8*)(wsp + WP2B), mt64, nt1, SMEM + S_X3A, 104, lane, a1);
    {
        int ch0 = mt64 * 16 + h * 4;
        int pt = p16 + nt1 * 16;
        float vv[4] = {fmaxf(a1[0].x, 0.f), fmaxf(a1[0].y, 0.f),
                       fmaxf(a1[0].z, 0.f), fmaxf(a1[0].w, 0.f)};
        ushort4 u;
        u.x = f2bf(vv[0]); u.y = f2bf(vv[1]); u.z = f2bf(vv[2]); u.w = f2bf(vv[3]);
        *(ushort4*)(SMEM + S_X3B + pt * 104 + ch0) = u;
        #pragma unroll
        for (int r = 0; r < 4; ++r)
            out[OUT_SHAL + ((size_t)(b * 64 + ch0 + r)) * N_PTS + n0 + pt] = vv[r];
    }
    __syncthreads();

    // LIN(real) + cosine partials
    mfma_tiles<3, 1>((const short8*)(wsp + WLIN), mt64, nt1, SMEM + S_X3B, 104, lane, srvA);
    {
        f32x4 sr = srvA[0], si = sivA[0];
        float pn = sr.x * si.x + sr.y * si.y + sr.z * si.z + sr.w * si.w;
        float pr = sr.x * sr.x + sr.y * sr.y + sr.z * sr.z + sr.w * sr.w;
        float pi = si.x * si.x + si.y * si.y + si.z * si.z + si.w * si.w;
        pn += __shfl_xor(pn, 16, 64); pn += __shfl_xor(pn, 32, 64);
        pr += __shfl_xor(pr, 16, 64); pr += __shfl_xor(pr, 32, 64);
        pi += __shfl_xor(pi, 16, 64); pi += __shfl_xor(pi, 32, 64);
        if (lane < 16) {
            RBUF[0][wid][p16] = pn;
            RBUF[1][wid][p16] = pr;
            RBUF[2][wid][p16] = pi;
        }
    }
    __syncthreads();

    // ================= similarity ==========================================
    if (tid < 32) {
        int pt = tid, q = pt >> 4, pp = pt & 15;
        float num = 0.f, rr = 0.f, ii = 0.f;
        #pragma unroll
        for (int m = 0; m < 4; ++m) {
            num += RBUF[0][q * 4 + m][pp];
            rr  += RBUF[1][q * 4 + m][pp];
            ii  += RBUF[2][q * 4 + m][pp];
        }
        float den = fmaxf(sqrtf(rr) * sqrtf(ii), 1e-8f);
        float geo = expf(-(1.0f / fw1p[0]) * DMIN[pt]) + fw2p[0];
        float sim = (num / den) * geo;
        SIMB[pt] = sim;
        out[OUT_SIM  + (size_t)b * N_PTS + n0 + pt] = sim;
        out[OUT_DSIM + (size_t)b * N_PTS + n0 + pt] = fw3p[0];
    }
    __syncthreads();

    // ================= F2 = sim*f2d, X4 statics (overlay X1) ===============
    {
        int pt = tid & 31, cg = tid >> 5;                // 16 ch-groups of 4
        float s = SIMB[pt];
        const float* base = f2d + ((size_t)(b * 64 + cg * 4)) * N_PTS + n0 + pt;
        ushort4 u;
        u.x = f2bf(s * base[0]);
        u.y = f2bf(s * base[(size_t)N_PTS]);
        u.z = f2bf(s * base[2 * (size_t)N_PTS]);
        u.w = f2bf(s * base[3 * (size_t)N_PTS]);
        *(ushort4*)(SMEM + S_F2 + pt * 104 + cg * 4) = u;
    }
    for (int e = tid; e < 32 * 32; e += 512) {           // F2 ch64 bias, 65..95 zero
        int pt = e >> 5, c = 64 + (e & 31);
        SMEM[S_F2 + pt * 104 + c] = (c == 64) ? 0x3F80 : 0;
    }
    if (tid < 96) {                                      // X4 pts ch 64..66 (from global)
        int c = tid >> 5, pt = tid & 31;
        SMEM[S_X4 + pt * 104 + 64 + c] = f2bf(pts[((size_t)(b * 3 + c)) * N_PTS + n0 + pt]);
    }
    for (int e = tid; e < 32 * 29; e += 512) {           // X4 bias@67, zeros 68..95
        int pt = e / 29, c = 67 + e % 29;
        SMEM[S_X4 + pt * 104 + c] = (c == 67) ? 0x3F80 : 0;
    }
    __syncthreads();

    // ================= C3A: [shal(X3B) ; F2] -> X3A ========================
    {
        const short8* W = (const short8*)(wsp + WC3A);
        a1[0] = (f32x4){0.f, 0.f, 0.f, 0.f};
        int row = (p16 + nt1 * 16) * 104 + (h << 3);
        #pragma unroll
        for (int ks = 0; ks < 5; ++ks) {
            short8 a = W[(mt64 * 5 + ks) * 64 + lane];
            const ushort_t* src = (ks < 2)
                ? (SMEM + S_X3B + row + ks * 32)
                : (SMEM + S_F2  + row + (ks - 2) * 32);
            a1[0] = __builtin_amdgcn_mfma_f32_16x16x32_bf16(a, *(const short8*)src, a1[0], 0, 0, 0);
        }
        epi_relu_lds<1>(a1, mt64, nt1, h, p16, SMEM + S_X3A, 104);
    }
    __syncthreads();

    // ================= C3B -> X4 ch0..63 ===================================
    mfma_tiles<3, 1>((const short8*)(wsp + WC3B), mt64, nt1, SMEM + S_X3A, 104, lane, a1);
    epi_relu_lds<1>(a1, mt64, nt1, h, p16, SMEM + S_X4, 104);
    __syncthreads();

    // ================= PN2: X4 -> deeprealfeat =============================
    mfma_tiles<3, 2>((const short8*)(wsp + WPN), wid, 0, SMEM + S_X4, 104, lane, a2);
    {
        int ch0 = wid * 16 + h * 4;
        #pragma unroll
        for (int t = 0; t < 2; ++t) {
            int pt = p16 + t * 16;
            #pragma unroll
            for (int r = 0; r < 4; ++r) {
                float v = fmaxf(((const float*)&a2[t])[r], 0.f);
                out[OUT_DEEP + ((size_t)(b * 128 + ch0 + r)) * N_PTS + n0 + pt] = v;
            }
        }
    }
}

extern "C" void kernel_launch(void* const* d_in, const int* in_sizes, int n_in,
                              void* d_out, int out_size, void* d_ws, size_t ws_size,
                              hipStream_t stream) {
    const float* img    = (const float*)d_in[0];
    const float* knn    = (const float*)d_in[1];
    const float* pts    = (const float*)d_in[2];
    const float* f2d    = (const float*)d_in[3];
    const float* sift_W = (const float*)d_in[4];
    const float* sift_b = (const float*)d_in[5];
    const float* sift_g = (const float*)d_in[6];
    const float* sift_bt= (const float*)d_in[7];
    const float* c2_W1  = (const float*)d_in[8];
    const float* c2_b1  = (const float*)d_in[9];
    const float* c2_g1  = (const float*)d_in[10];
    const float* c2_bt1 = (const float*)d_in[11];
    const float* c2_W2  = (const float*)d_in[12];
    const float* c2_b2  = (const float*)d_in[13];
    const float* c2_g2  = (const float*)d_in[14];
    const float* c2_bt2 = (const float*)d_in[15];
    const float* lin1_W = (const float*)d_in[16];
    const float* lin1_b = (const float*)d_in[17];
    const float* c3_W1  = (const float*)d_in[18];
    const float* c3_b1  = (const float*)d_in[19];
    const float* c3_g1  = (const float*)d_in[20];
    const float* c3_bt1 = (const float*)d_in[21];
    const float* c3_W2  = (const float*)d_in[22];
    const float* c3_b2  = (const float*)d_in[23];
    const float* c3_g2  = (const float*)d_in[24];
    const float* c3_bt2 = (const float*)d_in[25];
    const float* pn2_W  = (const float*)d_in[26];
    const float* pn2_b  = (const float*)d_in[27];
    const float* pn2_g  = (const float*)d_in[28];
    const float* pn2_bt = (const float*)d_in[29];
    const float* fw1    = (const float*)d_in[30];
    const float* fw2    = (const float*)d_in[31];
    const float* fw3    = (const float*)d_in[32];

    ushort_t* wsp = (ushort_t*)d_ws;
    float* out = (float*)d_out;

    auto prep = [&](const float* W, const float* bb, const float* g, const float* bt,
                    int off, int in_c, int MT, int KS, int mode, int has_bn) {
        int total = MT * KS * 64;
        prep_pack<<<(total + 255) / 256, 256, 0, stream>>>(
            W, bb, g, bt, wsp + off, in_c, MT, KS, mode, has_bn);
    };
    prep(sift_W, sift_b, sift_g, sift_bt, WP1, 195, 8, 7, 1, 1);
    prep(c2_W1,  c2_b1,  c2_g1,  c2_bt1, WP2A, 128, 4, 5, 0, 1);
    prep(c2_W2,  c2_b2,  c2_g2,  c2_bt2, WP2B,  64, 4, 3, 0, 1);
    prep(lin1_W, lin1_b, lin1_b, lin1_b, WLIN,  64, 4, 3, 0, 0);
    prep(c3_W1,  c3_b1,  c3_g1,  c3_bt1, WC3A, 128, 4, 5, 0, 1);
    prep(c3_W2,  c3_b2,  c3_g2,  c3_bt2, WC3B,  64, 4, 3, 0, 1);
    prep(pn2_W,  pn2_b,  pn2_g,  pn2_bt, WPN,   67, 8, 3, 2, 1);

    fused_all<<<1024, 512, 0, stream>>>(img, knn, pts, f2d, fw1, fw2, fw3, wsp, out);
}

// Round 5
// 66.945 us; speedup vs baseline: 6.8352x; 1.4387x over previous
//
#include <hip/hip_runtime.h>
#include <hip/hip_bf16.h>
#include <math.h>

typedef __attribute__((ext_vector_type(8))) short short8;
typedef __attribute__((ext_vector_type(4))) float f32x4;
typedef unsigned short ushort_t;

#define N_PTS 8192

// packed-weight offsets in ws (ushort units), fragment order [(mt*KS+ks)*64+lane][8]
#define WP1   0       // MT8 KS7
#define WP2A  28672   // MT4 KS5
#define WP2B  38912   // MT4 KS3
#define WLIN  45056   // MT4 KS3
#define WC3A  51200   // MT4 KS5
#define WC3B  61440   // MT4 KS3
#define WPN   67584   // MT8 KS3

// output float offsets
#define OUT_SIM  0
#define OUT_DSIM 32768
#define OUT_SHAL 65536
#define OUT_DEEP 2162688   // 65536 + 4*64*8192

// LDS carve (ushort units), 16 points => 32 rows (0..15 real, 16..31 img)
#define S_X1  0        // [32][232] -> 7424
#define S_X2  7424     // [32][168] -> end 12800
#define S_X3A 12800    // [32][104] -> end 16128
#define S_X3B 16128    // [32][104] -> end 19456
#define S_X4  0        // overlay X1: [16][104] -> 1664
#define S_F2  1664     // overlay X1: [16][104] -> 3328

__device__ __forceinline__ ushort_t f2bf(float x) {
    __hip_bfloat16 hv = __float2bfloat16(x);
    return *reinterpret_cast<ushort_t*>(&hv);
}
__device__ __forceinline__ float bf2f(ushort_t h) {
    return __uint_as_float(((unsigned)h) << 16);
}

// ---- weight pack: fragment-order bf16, BN-folded, bias as extra channel ----
__global__ void prep_pack(const float* __restrict__ W, const float* __restrict__ b,
                          const float* __restrict__ g, const float* __restrict__ bt,
                          ushort_t* __restrict__ WP, int in_c, int MT, int KS,
                          int mode, int has_bn) {
    int t = blockIdx.x * 256 + threadIdx.x;
    int total = MT * KS * 64;
    if (t >= total) return;
    int lane = t & 63, u = t >> 6, ks = u % KS, mt = u / KS;
    int m  = mt * 16 + (lane & 15);
    int k0 = ks * 32 + ((lane >> 4) << 3);
    float scale = has_bn ? g[m] : 1.0f;
    float bias  = has_bn ? fmaf(g[m], b[m], bt[m]) : b[m];
    ushort_t o[8];
    #pragma unroll
    for (int i = 0; i < 8; ++i) {
        int k = k0 + i; float v = 0.0f;
        if (mode == 1) {          // L1: k = [repre 0..191 ; pts 192..194 ; bias 195]
            if (k < 192)      v = W[m * 195 + 3 + k] * scale;
            else if (k < 195) v = W[m * 195 + (k - 192)] * scale;
            else if (k == 195) v = bias;
        } else if (mode == 2) {   // PN2: k = [fused 0..63 ; pts 64..66 ; bias 67]
            if (k < 64)       v = W[m * 67 + 3 + k] * scale;
            else if (k < 67)  v = W[m * 67 + (k - 64)] * scale;
            else if (k == 67) v = bias;
        } else {                  // identity + bias@in_c
            if (k < in_c)       v = W[m * in_c + k] * scale;
            else if (k == in_c) v = bias;
        }
        o[i] = f2bf(v);
    }
    ushort4 lo, hi;
    lo.x = o[0]; lo.y = o[1]; lo.z = o[2]; lo.w = o[3];
    hi.x = o[4]; hi.y = o[5]; hi.z = o[6]; hi.w = o[7];
    *(ushort4*)(WP + t * 8)     = lo;
    *(ushort4*)(WP + t * 8 + 4) = hi;
}

template<int KS, int NTS>
__device__ __forceinline__ void mfma_tiles(const short8* __restrict__ WP, int mt, int nt0,
                                           const ushort_t* __restrict__ Xin, int sin,
                                           int lane, f32x4 acc[NTS]) {
    #pragma unroll
    for (int t = 0; t < NTS; ++t) acc[t] = (f32x4){0.f, 0.f, 0.f, 0.f};
    #pragma unroll
    for (int ks = 0; ks < KS; ++ks) {
        short8 a = WP[(mt * KS + ks) * 64 + lane];
        #pragma unroll
        for (int t = 0; t < NTS; ++t) {
            const short8 bv = *(const short8*)(Xin + ((lane & 15) + (nt0 + t) * 16) * sin
                                               + ks * 32 + ((lane >> 4) << 3));
            acc[t] = __builtin_amdgcn_mfma_f32_16x16x32_bf16(a, bv, acc[t], 0, 0, 0);
        }
    }
}

template<int NTS>
__device__ __forceinline__ void epi_relu_lds(const f32x4 acc[NTS], int mt, int nt0,
                                             int h, int p, ushort_t* Xout, int sout) {
    int ch0 = mt * 16 + h * 4;
    #pragma unroll
    for (int t = 0; t < NTS; ++t) {
        int pt = p + (nt0 + t) * 16;
        ushort4 u;
        u.x = f2bf(fmaxf(acc[t].x, 0.f)); u.y = f2bf(fmaxf(acc[t].y, 0.f));
        u.z = f2bf(fmaxf(acc[t].z, 0.f)); u.w = f2bf(fmaxf(acc[t].w, 0.f));
        *(ushort4*)(Xout + pt * sout + ch0) = u;
    }
}

__global__ __launch_bounds__(512, 8)
void fused_all(const float* __restrict__ img,   // [4][3][8192][64]
               const float* __restrict__ knn,   // [4][3][64][8192]
               const float* __restrict__ pts,   // [4][3][8192]
               const float* __restrict__ f2d,   // [4][64][8192]
               const float* __restrict__ fw1p, const float* __restrict__ fw2p,
               const float* __restrict__ fw3p,
               const ushort_t* __restrict__ wsp, float* __restrict__ out)
{
    __shared__ ushort_t SMEM[19456];
    __shared__ float DMIN[16];
    __shared__ float RBUF[3][4][16];

    const int tid  = threadIdx.x;
    const int wid  = __builtin_amdgcn_readfirstlane(tid >> 6);
    const int lane = tid & 63;
    const int p16  = lane & 15;
    const int h    = lane >> 4;
    const int b    = blockIdx.x >> 9;          // 2048 blocks = 4 b x 512 tiles
    const int n0   = (blockIdx.x & 511) << 4;  // 16 points per tile

    const int mt64 = wid & 3;
    const int nt1  = wid >> 2;

    f32x4 a2[2], a1[1];
    float fpre[4] = {0.f, 0.f, 0.f, 0.f};
    const short8 zero8 = {0, 0, 0, 0, 0, 0, 0, 0};

    // ================= phase 0: pads + stage knn(rows 0..15) + img(16..31) ==
    for (int e = tid; e < 32 * 29; e += 512) {           // X1 ch195 bias, 196..223 zero
        int r = e / 29, c = 195 + e % 29;
        SMEM[S_X1 + r * 232 + c] = (c == 195) ? 0x3F80 : 0;
    }
    for (int e = tid; e < 32 * 32; e += 512) {           // X2 ch128 bias, 129..159 zero
        int r = e >> 5, c = 128 + (e & 31);
        SMEM[S_X2 + r * 168 + c] = (c == 128) ? 0x3F80 : 0;
    }
    for (int e = tid; e < 32 * 32; e += 512) {           // X3A/X3B ch64 bias, 65..95 zero
        int r = e >> 5, c = 64 + (e & 31);
        ushort_t v = (c == 64) ? 0x3F80 : 0;
        SMEM[S_X3A + r * 104 + c] = v;
        SMEM[S_X3B + r * 104 + c] = v;
    }
    {   // knn -> rows 0..15, ch 0..191 (ch = c*64+k); 6 consecutive ch per thread
        int pt = tid & 15, g = tid >> 4;                 // g 0..31
        #pragma unroll
        for (int jp = 0; jp < 3; ++jp) {
            int ck = g * 6 + jp * 2;
            int c = ck >> 6, k = ck & 63;
            const float* base = knn + ((size_t)(b * 3 + c) * 64 + k) * N_PTS + n0 + pt;
            ushort2 u;
            u.x = f2bf(base[0]);
            u.y = f2bf(base[(size_t)N_PTS]);
            *(ushort2*)(SMEM + S_X1 + pt * 232 + ck) = u;
        }
    }
    {   // img -> rows 16..31, ch 0..191
        int pt = tid >> 5, q = tid & 31;
        #pragma unroll
        for (int c = 0; c < 3; ++c) {
            float2 v = *(const float2*)(img + (((size_t)(b * 3 + c)) * N_PTS + n0 + pt) * 64 + q * 2);
            ushort2 u;
            u.x = f2bf(v.x); u.y = f2bf(v.y);
            *(ushort2*)(SMEM + S_X1 + (16 + pt) * 232 + c * 64 + q * 2) = u;
        }
    }
    if (tid < 96) {                                      // pts ch 192..194, all 32 rows
        int c = tid >> 5, r = tid & 31;
        SMEM[S_X1 + r * 232 + 192 + c] = f2bf(pts[((size_t)(b * 3 + c)) * N_PTS + n0 + (r & 15)]);
    }
    __syncthreads();   // B1

    // ================= phase 1: L1 (32 rows) + dist ========================
    mfma_tiles<7, 2>((const short8*)(wsp + WP1), wid, 0, SMEM + S_X1, 232, lane, a2);
    epi_relu_lds<2>(a2, wid, 0, h, p16, SMEM + S_X2, 168);

    #pragma unroll 1
    for (int j = 0; j < 2; ++j) {                        // 2 points per wave
        int pt = wid * 2 + j;
        const ushort_t* rrow = SMEM + S_X1 + pt * 232;
        const ushort_t* irow = SMEM + S_X1 + (16 + pt) * 232;
        float px = bf2f(rrow[192]), py = bf2f(rrow[193]), pz = bf2f(rrow[194]);
        short8 bfr[4];
        #pragma unroll
        for (int lt = 0; lt < 4; ++lt) {                 // hoisted image B-frags
            int l = lt * 16 + p16;
            float fx = bf2f(irow[l]) - px;
            float fy = bf2f(irow[64 + l]) - py;
            float fz = bf2f(irow[128 + l]) - pz;
            float i2 = fmaf(fx, fx, fmaf(fy, fy, fz * fz));
            short8 t = zero8;
            if (h == 0) {
                t[0] = (short)f2bf(fx); t[1] = (short)f2bf(fy); t[2] = (short)f2bf(fz);
                t[3] = (short)0x3F80;   t[4] = (short)f2bf(i2);
            }
            bfr[lt] = t;
        }
        f32x4 m4 = (f32x4){3.0e38f, 3.0e38f, 3.0e38f, 3.0e38f};
        #pragma unroll 1
        for (int kt = 0; kt < 4; ++kt) {
            int k = kt * 16 + p16;
            float rx = bf2f(rrow[k]) - px;
            float ry = bf2f(rrow[64 + k]) - py;
            float rz = bf2f(rrow[128 + k]) - pz;
            float r2 = fmaf(rx, rx, fmaf(ry, ry, rz * rz));
            short8 af = zero8;
            if (h == 0) {
                af[0] = (short)f2bf(-2.0f * rx);
                af[1] = (short)f2bf(-2.0f * ry);
                af[2] = (short)f2bf(-2.0f * rz);
                af[3] = (short)f2bf(r2);
                af[4] = (short)0x3F80;
            }
            #pragma unroll
            for (int lt = 0; lt < 4; ++lt) {
                f32x4 acc = __builtin_amdgcn_mfma_f32_16x16x32_bf16(af, bfr[lt],
                                (f32x4){0.f, 0.f, 0.f, 0.f}, 0, 0, 0);
                m4.x = fminf(m4.x, acc.x); m4.y = fminf(m4.y, acc.y);
                m4.z = fminf(m4.z, acc.z); m4.w = fminf(m4.w, acc.w);
            }
        }
        float v = fminf(fminf(m4.x, m4.y), fminf(m4.z, m4.w));
        #pragma unroll
        for (int off = 32; off > 0; off >>= 1)
            v = fminf(v, __shfl_xor(v, off, 64));
        if (lane == 0) DMIN[pt] = v;
    }
    __syncthreads();   // B2

    // ================= phase 2: L2A (32 rows) ==============================
    mfma_tiles<5, 1>((const short8*)(wsp + WP2A), mt64, nt1, SMEM + S_X2, 168, lane, a1);
    epi_relu_lds<1>(a1, mt64, nt1, h, p16, SMEM + S_X3A, 104);
    __syncthreads();   // B3

    // ================= phase 3: L2B (32 rows) + SHAL stores ================
    mfma_tiles<3, 1>((const short8*)(wsp + WP2B), mt64, nt1, SMEM + S_X3A, 104, lane, a1);
    {
        int ch0 = mt64 * 16 + h * 4;
        int row = p16 + nt1 * 16;
        float v0 = fmaxf(a1[0].x, 0.f), v1 = fmaxf(a1[0].y, 0.f);
        float v2 = fmaxf(a1[0].z, 0.f), v3 = fmaxf(a1[0].w, 0.f);
        ushort4 u;
        u.x = f2bf(v0); u.y = f2bf(v1); u.z = f2bf(v2); u.w = f2bf(v3);
        *(ushort4*)(SMEM + S_X3B + row * 104 + ch0) = u;
        if (nt1 == 0) {
            size_t base = OUT_SHAL + ((size_t)(b * 64 + ch0)) * N_PTS + n0 + p16;
            out[base]             = v0;
            out[base + N_PTS]     = v1;
            out[base + 2 * N_PTS] = v2;
            out[base + 3 * N_PTS] = v3;
        }
    }
    __syncthreads();   // B4

    // ============ phase 4: LIN (waves 0..3) | statics+preload (4..7) =======
    if (wid < 4) {
        f32x4 sv[2];
        mfma_tiles<3, 2>((const short8*)(wsp + WLIN), wid, 0, SMEM + S_X3B, 104, lane, sv);
        // sv[0]=real rows, sv[1]=img rows, same point p16
        float pn = sv[0].x * sv[1].x + sv[0].y * sv[1].y + sv[0].z * sv[1].z + sv[0].w * sv[1].w;
        float pr = sv[0].x * sv[0].x + sv[0].y * sv[0].y + sv[0].z * sv[0].z + sv[0].w * sv[0].w;
        float pi = sv[1].x * sv[1].x + sv[1].y * sv[1].y + sv[1].z * sv[1].z + sv[1].w * sv[1].w;
        pn += __shfl_xor(pn, 16, 64); pn += __shfl_xor(pn, 32, 64);
        pr += __shfl_xor(pr, 16, 64); pr += __shfl_xor(pr, 32, 64);
        pi += __shfl_xor(pi, 16, 64); pi += __shfl_xor(pi, 32, 64);
        if (lane < 16) {
            RBUF[0][wid][p16] = pn;
            RBUF[1][wid][p16] = pr;
            RBUF[2][wid][p16] = pi;
        }
    } else {
        int t256 = tid - 256;                            // 0..255
        int pt = t256 & 15, cg = t256 >> 4;              // cg 0..15 -> ch cg*4..+3
        #pragma unroll
        for (int r = 0; r < 4; ++r)
            fpre[r] = f2d[((size_t)(b * 64 + cg * 4 + r)) * N_PTS + n0 + pt];
        for (int e = t256; e < 16 * 32; e += 256) {      // X4 statics ch64..95
            int r = e >> 5, c = 64 + (e & 31);
            ushort_t v = 0;
            if (c < 67)       v = f2bf(pts[((size_t)(b * 3 + (c - 64))) * N_PTS + n0 + r]);
            else if (c == 67) v = 0x3F80;
            SMEM[S_X4 + r * 104 + c] = v;
        }
        for (int e = t256; e < 16 * 32; e += 256) {      // F2 pads ch64..95
            int r = e >> 5, c = 64 + (e & 31);
            SMEM[S_F2 + r * 104 + c] = (c == 64) ? 0x3F80 : 0;
        }
    }
    __syncthreads();   // B5

    // ============ phase 5: sim (redundant per-thread) + F2 fill ============
    if (wid >= 4) {
        int t256 = tid - 256;
        int pt = t256 & 15, cg = t256 >> 4;
        float num = 0.f, rr = 0.f, ii = 0.f;
        #pragma unroll
        for (int m = 0; m < 4; ++m) {
            num += RBUF[0][m][pt];
            rr  += RBUF[1][m][pt];
            ii  += RBUF[2][m][pt];
        }
        float den = fmaxf(sqrtf(rr) * sqrtf(ii), 1e-8f);
        float geo = expf(-(1.0f / fw1p[0]) * DMIN[pt]) + fw2p[0];
        float sim = (num / den) * geo;
        ushort4 u;
        u.x = f2bf(sim * fpre[0]); u.y = f2bf(sim * fpre[1]);
        u.z = f2bf(sim * fpre[2]); u.w = f2bf(sim * fpre[3]);
        *(ushort4*)(SMEM + S_F2 + pt * 104 + cg * 4) = u;
        if (cg == 0) {
            out[OUT_SIM  + (size_t)b * N_PTS + n0 + pt] = sim;
            out[OUT_DSIM + (size_t)b * N_PTS + n0 + pt] = fw3p[0];
        }
    }
    __syncthreads();   // B6

    // ============ phase 6: C3A [X3B real ; F2] -> X3A rows 0..15 ===========
    if (wid < 4) {
        const short8* W = (const short8*)(wsp + WC3A);
        f32x4 a = (f32x4){0.f, 0.f, 0.f, 0.f};
        int row = p16 * 104 + (h << 3);
        #pragma unroll
        for (int ks = 0; ks < 5; ++ks) {
            short8 aw = W[(wid * 5 + ks) * 64 + lane];
            const ushort_t* src = (ks < 2)
                ? (SMEM + S_X3B + row + ks * 32)
                : (SMEM + S_F2  + row + (ks - 2) * 32);
            a = __builtin_amdgcn_mfma_f32_16x16x32_bf16(aw, *(const short8*)src, a, 0, 0, 0);
        }
        a1[0] = a;
        epi_relu_lds<1>(a1, wid, 0, h, p16, SMEM + S_X3A, 104);
    }
    __syncthreads();   // B7

    // ============ phase 7: C3B -> X4 ch0..63 rows 0..15 ====================
    if (wid < 4) {
        mfma_tiles<3, 1>((const short8*)(wsp + WC3B), wid, 0, SMEM + S_X3A, 104, lane, a1);
        epi_relu_lds<1>(a1, wid, 0, h, p16, SMEM + S_X4, 104);
    }
    __syncthreads();   // B8

    // ============ phase 8: PN2 -> deeprealfeat =============================
    mfma_tiles<3, 1>((const short8*)(wsp + WPN), wid, 0, SMEM + S_X4, 104, lane, a1);
    {
        int ch0 = wid * 16 + h * 4;
        size_t base = OUT_DEEP + ((size_t)(b * 128 + ch0)) * N_PTS + n0 + p16;
        out[base]             = fmaxf(a1[0].x, 0.f);
        out[base + N_PTS]     = fmaxf(a1[0].y, 0.f);
        out[base + 2 * N_PTS] = fmaxf(a1[0].z, 0.f);
        out[base + 3 * N_PTS] = fmaxf(a1[0].w, 0.f);
    }
}

extern "C" void kernel_launch(void* const* d_in, const int* in_sizes, int n_in,
                              void* d_out, int out_size, void* d_ws, size_t ws_size,
                              hipStream_t stream) {
    const float* img    = (const float*)d_in[0];
    const float* knn    = (const float*)d_in[1];
    const float* pts    = (const float*)d_in[2];
    const float* f2d    = (const float*)d_in[3];
    const float* sift_W = (const float*)d_in[4];
    const float* sift_b = (const float*)d_in[5];
    const float* sift_g = (const float*)d_in[6];
    const float* sift_bt= (const float*)d_in[7];
    const float* c2_W1  = (const float*)d_in[8];
    const float* c2_b1  = (const float*)d_in[9];
    const float* c2_g1  = (const float*)d_in[10];
    const float* c2_bt1 = (const float*)d_in[11];
    const float* c2_W2  = (const float*)d_in[12];
    const float* c2_b2  = (const float*)d_in[13];
    const float* c2_g2  = (const float*)d_in[14];
    const float* c2_bt2 = (const float*)d_in[15];
    const float* lin1_W = (const float*)d_in[16];
    const float* lin1_b = (const float*)d_in[17];
    const float* c3_W1  = (const float*)d_in[18];
    const float* c3_b1  = (const float*)d_in[19];
    const float* c3_g1  = (const float*)d_in[20];
    const float* c3_bt1 = (const float*)d_in[21];
    const float* c3_W2  = (const float*)d_in[22];
    const float* c3_b2  = (const float*)d_in[23];
    const float* c3_g2  = (const float*)d_in[24];
    const float* c3_bt2 = (const float*)d_in[25];
    const float* pn2_W  = (const float*)d_in[26];
    const float* pn2_b  = (const float*)d_in[27];
    const float* pn2_g  = (const float*)d_in[28];
    const float* pn2_bt = (const float*)d_in[29];
    const float* fw1    = (const float*)d_in[30];
    const float* fw2    = (const float*)d_in[31];
    const float* fw3    = (const float*)d_in[32];

    ushort_t* wsp = (ushort_t*)d_ws;
    float* out = (float*)d_out;

    auto prep = [&](const float* W, const float* bb, const float* g, const float* bt,
                    int off, int in_c, int MT, int KS, int mode, int has_bn) {
        int total = MT * KS * 64;
        prep_pack<<<(total + 255) / 256, 256, 0, stream>>>(
            W, bb, g, bt, wsp + off, in_c, MT, KS, mode, has_bn);
    };
    prep(sift_W, sift_b, sift_g, sift_bt, WP1, 195, 8, 7, 1, 1);
    prep(c2_W1,  c2_b1,  c2_g1,  c2_bt1, WP2A, 128, 4, 5, 0, 1);
    prep(c2_W2,  c2_b2,  c2_g2,  c2_bt2, WP2B,  64, 4, 3, 0, 1);
    prep(lin1_W, lin1_b, lin1_b, lin1_b, WLIN,  64, 4, 3, 0, 0);
    prep(c3_W1,  c3_b1,  c3_g1,  c3_bt1, WC3A, 128, 4, 5, 0, 1);
    prep(c3_W2,  c3_b2,  c3_g2,  c3_bt2, WC3B,  64, 4, 3, 0, 1);
    prep(pn2_W,  pn2_b,  pn2_g,  pn2_bt, WPN,   67, 8, 3, 2, 1);

    fused_all<<<2048, 512, 0, stream>>>(img, knn, pts, f2d, fw1, fw2, fw3, wsp, out);
}

// Round 6
// 44.546 us; speedup vs baseline: 10.2722x; 1.5028x over previous
//
#include <hip/hip_runtime.h>
#include <hip/hip_bf16.h>
#include <math.h>

typedef __attribute__((ext_vector_type(8))) short short8;
typedef __attribute__((ext_vector_type(4))) float f32x4;
typedef __attribute__((ext_vector_type(16))) float f32x16;
typedef unsigned short ushort_t;

#define N_PTS 8192

// packed-weight offsets in ws (ushort units), fragment order [(mt*KS+ks)*64+lane][8]
#define WP1   0       // MT8 KS7
#define WP2A  28672   // MT4 KS5
#define WP2B  38912   // MT4 KS3
#define WLIN  45056   // MT4 KS3
#define WC3A  51200   // MT4 KS5
#define WC3B  61440   // MT4 KS3
#define WPN   67584   // MT8 KS3

// output float offsets
#define OUT_SIM  0
#define OUT_DSIM 32768
#define OUT_SHAL 65536
#define OUT_DEEP 2162688   // 65536 + 4*64*8192

// LDS carve (ushort units), 16 points => 32 rows (0..15 real, 16..31 img)
#define S_X1  0        // [32][232] -> 7424
#define S_X2  7424     // [32][168] -> end 12800
#define S_X3A 12800    // [32][104] -> end 16128
#define S_X3B 16128    // [32][104] -> end 19456
#define S_X4  0        // overlay X1: [16][104] -> 1664
#define S_F2  1664     // overlay X1: [16][104] -> 3328

__device__ __forceinline__ ushort_t f2bf(float x) {
    __hip_bfloat16 hv = __float2bfloat16(x);
    return *reinterpret_cast<ushort_t*>(&hv);
}
__device__ __forceinline__ float bf2f(ushort_t h) {
    return __uint_as_float(((unsigned)h) << 16);
}

// ---- single fused weight pack: all 7 layers in one launch ------------------
__global__ __launch_bounds__(256)
void prep_all(const float* __restrict__ sW, const float* __restrict__ sb,
              const float* __restrict__ sg, const float* __restrict__ sbt,
              const float* __restrict__ aW, const float* __restrict__ ab,
              const float* __restrict__ ag, const float* __restrict__ abt,
              const float* __restrict__ bW, const float* __restrict__ bb_,
              const float* __restrict__ bg, const float* __restrict__ bbt,
              const float* __restrict__ lW, const float* __restrict__ lb,
              const float* __restrict__ cW, const float* __restrict__ cb,
              const float* __restrict__ cg, const float* __restrict__ cbt,
              const float* __restrict__ dW, const float* __restrict__ db,
              const float* __restrict__ dg, const float* __restrict__ dbt,
              const float* __restrict__ pW, const float* __restrict__ pb,
              const float* __restrict__ pg, const float* __restrict__ pbt,
              ushort_t* __restrict__ wsp) {
    int g = blockIdx.x * 256 + threadIdx.x;   // 0..9983 fragment-groups
    const float *W, *B, *G, *BT;
    int in_c, KS, mode, has_bn, off;
    if (g < 3584)      {           W=sW; B=sb;  G=sg; BT=sbt; in_c=195; KS=7; mode=1; has_bn=1; off=WP1;  }
    else if (g < 4864) { g -= 3584; W=aW; B=ab;  G=ag; BT=abt; in_c=128; KS=5; mode=0; has_bn=1; off=WP2A; }
    else if (g < 5632) { g -= 4864; W=bW; B=bb_; G=bg; BT=bbt; in_c=64;  KS=3; mode=0; has_bn=1; off=WP2B; }
    else if (g < 6400) { g -= 5632; W=lW; B=lb;  G=lb; BT=lb;  in_c=64;  KS=3; mode=0; has_bn=0; off=WLIN; }
    else if (g < 7680) { g -= 6400; W=cW; B=cb;  G=cg; BT=cbt; in_c=128; KS=5; mode=0; has_bn=1; off=WC3A; }
    else if (g < 8448) { g -= 7680; W=dW; B=db;  G=dg; BT=dbt; in_c=64;  KS=3; mode=0; has_bn=1; off=WC3B; }
    else               { g -= 8448; W=pW; B=pb;  G=pg; BT=pbt; in_c=67;  KS=3; mode=2; has_bn=1; off=WPN;  }

    int lane = g & 63, u = g >> 6, ks = u % KS, mt = u / KS;
    int m  = mt * 16 + (lane & 15);
    int k0 = ks * 32 + ((lane >> 4) << 3);
    float scale = has_bn ? G[m] : 1.0f;
    float bias  = has_bn ? fmaf(G[m], B[m], BT[m]) : B[m];
    ushort_t o[8];
    #pragma unroll
    for (int i = 0; i < 8; ++i) {
        int k = k0 + i; float v = 0.0f;
        if (mode == 1) {          // L1: k = [repre 0..191 ; pts 192..194 ; bias 195]
            if (k < 192)      v = W[m * 195 + 3 + k] * scale;
            else if (k < 195) v = W[m * 195 + (k - 192)] * scale;
            else if (k == 195) v = bias;
        } else if (mode == 2) {   // PN2: k = [fused 0..63 ; pts 64..66 ; bias 67]
            if (k < 64)       v = W[m * 67 + 3 + k] * scale;
            else if (k < 67)  v = W[m * 67 + (k - 64)] * scale;
            else if (k == 67) v = bias;
        } else {                  // identity + bias@in_c
            if (k < in_c)       v = W[m * in_c + k] * scale;
            else if (k == in_c) v = bias;
        }
        o[i] = f2bf(v);
    }
    ushort4 lo, hi;
    lo.x = o[0]; lo.y = o[1]; lo.z = o[2]; lo.w = o[3];
    hi.x = o[4]; hi.y = o[5]; hi.z = o[6]; hi.w = o[7];
    int t = (((mt * KS + ks) * 64) + lane) * 8 + off;
    *(ushort4*)(wsp + t)     = lo;
    *(ushort4*)(wsp + t + 4) = hi;
}

template<int KS, int NTS>
__device__ __forceinline__ void mfma_tiles(const short8* __restrict__ WP, int mt, int nt0,
                                           const ushort_t* __restrict__ Xin, int sin,
                                           int lane, f32x4 acc[NTS]) {
    #pragma unroll
    for (int t = 0; t < NTS; ++t) acc[t] = (f32x4){0.f, 0.f, 0.f, 0.f};
    #pragma unroll
    for (int ks = 0; ks < KS; ++ks) {
        short8 a = WP[(mt * KS + ks) * 64 + lane];
        #pragma unroll
        for (int t = 0; t < NTS; ++t) {
            const short8 bv = *(const short8*)(Xin + ((lane & 15) + (nt0 + t) * 16) * sin
                                               + ks * 32 + ((lane >> 4) << 3));
            acc[t] = __builtin_amdgcn_mfma_f32_16x16x32_bf16(a, bv, acc[t], 0, 0, 0);
        }
    }
}

template<int NTS>
__device__ __forceinline__ void epi_relu_lds(const f32x4 acc[NTS], int mt, int nt0,
                                             int h, int p, ushort_t* Xout, int sout) {
    int ch0 = mt * 16 + h * 4;
    #pragma unroll
    for (int t = 0; t < NTS; ++t) {
        int pt = p + (nt0 + t) * 16;
        ushort4 u;
        u.x = f2bf(fmaxf(acc[t].x, 0.f)); u.y = f2bf(fmaxf(acc[t].y, 0.f));
        u.z = f2bf(fmaxf(acc[t].z, 0.f)); u.w = f2bf(fmaxf(acc[t].w, 0.f));
        *(ushort4*)(Xout + pt * sout + ch0) = u;
    }
}

__global__ __launch_bounds__(512, 8)
void fused_all(const float* __restrict__ img,   // [4][3][8192][64]
               const float* __restrict__ knn,   // [4][3][64][8192]
               const float* __restrict__ pts,   // [4][3][8192]
               const float* __restrict__ f2d,   // [4][64][8192]
               const float* __restrict__ fw1p, const float* __restrict__ fw2p,
               const float* __restrict__ fw3p,
               const ushort_t* __restrict__ wsp, float* __restrict__ out)
{
    __shared__ ushort_t SMEM[19456];
    __shared__ float DMIN[16];
    __shared__ float RBUF[3][4][16];

    const int tid  = threadIdx.x;
    const int wid  = __builtin_amdgcn_readfirstlane(tid >> 6);
    const int lane = tid & 63;
    const int p16  = lane & 15;
    const int h    = lane >> 4;
    const int b    = blockIdx.x >> 9;          // 2048 blocks = 4 b x 512 tiles
    const int n0   = (blockIdx.x & 511) << 4;  // 16 points per tile

    const int mt64 = wid & 3;
    const int nt1  = wid >> 2;

    f32x4 a2[2], a1[1];
    float fpre[4] = {0.f, 0.f, 0.f, 0.f};
    const short8 zero8 = {0, 0, 0, 0, 0, 0, 0, 0};

    // ================= phase 0: pads + stage knn(rows 0..15) + img(16..31) ==
    for (int e = tid; e < 32 * 29; e += 512) {           // X1 ch195 bias, 196..223 zero
        int r = e / 29, c = 195 + e % 29;
        SMEM[S_X1 + r * 232 + c] = (c == 195) ? 0x3F80 : 0;
    }
    for (int e = tid; e < 32 * 32; e += 512) {           // X2 ch128 bias, 129..159 zero
        int r = e >> 5, c = 128 + (e & 31);
        SMEM[S_X2 + r * 168 + c] = (c == 128) ? 0x3F80 : 0;
    }
    for (int e = tid; e < 32 * 32; e += 512) {           // X3A/X3B ch64 bias, 65..95 zero
        int r = e >> 5, c = 64 + (e & 31);
        ushort_t v = (c == 64) ? 0x3F80 : 0;
        SMEM[S_X3A + r * 104 + c] = v;
        SMEM[S_X3B + r * 104 + c] = v;
    }
    {   // knn -> rows 0..15, ch 0..191 (ch = c*64+k); 6 consecutive ch per thread
        int pt = tid & 15, g = tid >> 4;                 // g 0..31
        #pragma unroll
        for (int jp = 0; jp < 3; ++jp) {
            int ck = g * 6 + jp * 2;
            int c = ck >> 6, k = ck & 63;
            const float* base = knn + ((size_t)(b * 3 + c) * 64 + k) * N_PTS + n0 + pt;
            ushort2 u;
            u.x = f2bf(base[0]);
            u.y = f2bf(base[(size_t)N_PTS]);
            *(ushort2*)(SMEM + S_X1 + pt * 232 + ck) = u;
        }
    }
    {   // img -> rows 16..31, ch 0..191
        int pt = tid >> 5, q = tid & 31;
        #pragma unroll
        for (int c = 0; c < 3; ++c) {
            float2 v = *(const float2*)(img + (((size_t)(b * 3 + c)) * N_PTS + n0 + pt) * 64 + q * 2);
            ushort2 u;
            u.x = f2bf(v.x); u.y = f2bf(v.y);
            *(ushort2*)(SMEM + S_X1 + (16 + pt) * 232 + c * 64 + q * 2) = u;
        }
    }
    if (tid < 96) {                                      // pts ch 192..194, all 32 rows
        int c = tid >> 5, r = tid & 31;
        SMEM[S_X1 + r * 232 + 192 + c] = f2bf(pts[((size_t)(b * 3 + c)) * N_PTS + n0 + (r & 15)]);
    }
    __syncthreads();   // B1

    // ================= phase 1: L1 (32 rows) + dist (32x32 MFMA) ===========
    mfma_tiles<7, 2>((const short8*)(wsp + WP1), wid, 0, SMEM + S_X1, 232, lane, a2);
    epi_relu_lds<2>(a2, wid, 0, h, p16, SMEM + S_X2, 168);

    {
        const int m32 = lane & 31;
        const int h2  = lane >> 5;
        #pragma unroll 1
        for (int j = 0; j < 2; ++j) {                    // 2 points per wave
            int pt = wid * 2 + j;
            const ushort_t* rrow = SMEM + S_X1 + pt * 232;
            const ushort_t* irow = SMEM + S_X1 + (16 + pt) * 232;
            float px = bf2f(rrow[192]), py = bf2f(rrow[193]), pz = bf2f(rrow[194]);
            short8 af[2], bfr[2];
            #pragma unroll
            for (int c = 0; c < 2; ++c) {
                int k = c * 32 + m32;
                float rx = bf2f(rrow[k]) - px;
                float ry = bf2f(rrow[64 + k]) - py;
                float rz = bf2f(rrow[128 + k]) - pz;
                float r2 = fmaf(rx, rx, fmaf(ry, ry, rz * rz));
                short8 t = zero8;
                t[0] = (short)f2bf(-2.0f * rx); t[1] = (short)f2bf(-2.0f * ry);
                t[2] = (short)f2bf(-2.0f * rz); t[3] = (short)f2bf(r2);
                t[4] = (short)0x3F80;
                af[c] = h2 ? zero8 : t;
                float fx = bf2f(irow[k]) - px;
                float fy = bf2f(irow[64 + k]) - py;
                float fz = bf2f(irow[128 + k]) - pz;
                float i2 = fmaf(fx, fx, fmaf(fy, fy, fz * fz));
                short8 s = zero8;
                s[0] = (short)f2bf(fx); s[1] = (short)f2bf(fy); s[2] = (short)f2bf(fz);
                s[3] = (short)0x3F80;   s[4] = (short)f2bf(i2);
                bfr[c] = h2 ? zero8 : s;
            }
            float dmin = 3.0e38f;
            #pragma unroll
            for (int kc = 0; kc < 2; ++kc) {
                #pragma unroll
                for (int lc = 0; lc < 2; ++lc) {
                    f32x16 acc = {0.f,0.f,0.f,0.f,0.f,0.f,0.f,0.f,
                                  0.f,0.f,0.f,0.f,0.f,0.f,0.f,0.f};
                    acc = __builtin_amdgcn_mfma_f32_32x32x16_bf16(af[kc], bfr[lc], acc, 0, 0, 0);
                    #pragma unroll
                    for (int r = 0; r < 16; ++r) dmin = fminf(dmin, acc[r]);
                }
            }
            #pragma unroll
            for (int off = 32; off > 0; off >>= 1)
                dmin = fminf(dmin, __shfl_xor(dmin, off, 64));
            if (lane == 0) DMIN[pt] = dmin;
        }
    }
    __syncthreads();   // B2

    // ================= phase 2: L2A (32 rows) ==============================
    mfma_tiles<5, 1>((const short8*)(wsp + WP2A), mt64, nt1, SMEM + S_X2, 168, lane, a1);
    epi_relu_lds<1>(a1, mt64, nt1, h, p16, SMEM + S_X3A, 104);
    __syncthreads();   // B3

    // ================= phase 3: L2B (32 rows) + SHAL stores ================
    mfma_tiles<3, 1>((const short8*)(wsp + WP2B), mt64, nt1, SMEM + S_X3A, 104, lane, a1);
    {
        int ch0 = mt64 * 16 + h * 4;
        int row = p16 + nt1 * 16;
        float v0 = fmaxf(a1[0].x, 0.f), v1 = fmaxf(a1[0].y, 0.f);
        float v2 = fmaxf(a1[0].z, 0.f), v3 = fmaxf(a1[0].w, 0.f);
        ushort4 u;
        u.x = f2bf(v0); u.y = f2bf(v1); u.z = f2bf(v2); u.w = f2bf(v3);
        *(ushort4*)(SMEM + S_X3B + row * 104 + ch0) = u;
        if (nt1 == 0) {
            size_t base = OUT_SHAL + ((size_t)(b * 64 + ch0)) * N_PTS + n0 + p16;
            out[base]             = v0;
            out[base + N_PTS]     = v1;
            out[base + 2 * N_PTS] = v2;
            out[base + 3 * N_PTS] = v3;
        }
    }
    __syncthreads();   // B4

    // ============ phase 4: LIN (waves 0..3) | statics+preload (4..7) =======
    if (wid < 4) {
        f32x4 sv[2];
        mfma_tiles<3, 2>((const short8*)(wsp + WLIN), wid, 0, SMEM + S_X3B, 104, lane, sv);
        // sv[0]=real rows, sv[1]=img rows, same point p16
        float pn = sv[0].x * sv[1].x + sv[0].y * sv[1].y + sv[0].z * sv[1].z + sv[0].w * sv[1].w;
        float pr = sv[0].x * sv[0].x + sv[0].y * sv[0].y + sv[0].z * sv[0].z + sv[0].w * sv[0].w;
        float pi = sv[1].x * sv[1].x + sv[1].y * sv[1].y + sv[1].z * sv[1].z + sv[1].w * sv[1].w;
        pn += __shfl_xor(pn, 16, 64); pn += __shfl_xor(pn, 32, 64);
        pr += __shfl_xor(pr, 16, 64); pr += __shfl_xor(pr, 32, 64);
        pi += __shfl_xor(pi, 16, 64); pi += __shfl_xor(pi, 32, 64);
        if (lane < 16) {
            RBUF[0][wid][p16] = pn;
            RBUF[1][wid][p16] = pr;
            RBUF[2][wid][p16] = pi;
        }
    } else {
        int t256 = tid - 256;                            // 0..255
        int pt = t256 & 15, cg = t256 >> 4;              // cg 0..15 -> ch cg*4..+3
        #pragma unroll
        for (int r = 0; r < 4; ++r)
            fpre[r] = f2d[((size_t)(b * 64 + cg * 4 + r)) * N_PTS + n0 + pt];
        for (int e = t256; e < 16 * 32; e += 256) {      // X4 statics ch64..95
            int r = e >> 5, c = 64 + (e & 31);
            ushort_t v = 0;
            if (c < 67)       v = f2bf(pts[((size_t)(b * 3 + (c - 64))) * N_PTS + n0 + r]);
            else if (c == 67) v = 0x3F80;
            SMEM[S_X4 + r * 104 + c] = v;
        }
        for (int e = t256; e < 16 * 32; e += 256) {      // F2 pads ch64..95
            int r = e >> 5, c = 64 + (e & 31);
            SMEM[S_F2 + r * 104 + c] = (c == 64) ? 0x3F80 : 0;
        }
    }
    __syncthreads();   // B5

    // ============ phase 5: sim (redundant per-thread) + F2 fill ============
    if (wid >= 4) {
        int t256 = tid - 256;
        int pt = t256 & 15, cg = t256 >> 4;
        float num = 0.f, rr = 0.f, ii = 0.f;
        #pragma unroll
        for (int m = 0; m < 4; ++m) {
            num += RBUF[0][m][pt];
            rr  += RBUF[1][m][pt];
            ii  += RBUF[2][m][pt];
        }
        float den = fmaxf(sqrtf(rr) * sqrtf(ii), 1e-8f);
        float geo = expf(-(1.0f / fw1p[0]) * DMIN[pt]) + fw2p[0];
        float sim = (num / den) * geo;
        ushort4 u;
        u.x = f2bf(sim * fpre[0]); u.y = f2bf(sim * fpre[1]);
        u.z = f2bf(sim * fpre[2]); u.w = f2bf(sim * fpre[3]);
        *(ushort4*)(SMEM + S_F2 + pt * 104 + cg * 4) = u;
        if (cg == 0) {
            out[OUT_SIM  + (size_t)b * N_PTS + n0 + pt] = sim;
            out[OUT_DSIM + (size_t)b * N_PTS + n0 + pt] = fw3p[0];
        }
    }
    __syncthreads();   // B6

    // ============ phase 6: C3A [X3B real ; F2] -> X3A rows 0..15 ===========
    if (wid < 4) {
        const short8* W = (const short8*)(wsp + WC3A);
        f32x4 a = (f32x4){0.f, 0.f, 0.f, 0.f};
        int row = p16 * 104 + (h << 3);
        #pragma unroll
        for (int ks = 0; ks < 5; ++ks) {
            short8 aw = W[(wid * 5 + ks) * 64 + lane];
            const ushort_t* src = (ks < 2)
                ? (SMEM + S_X3B + row + ks * 32)
                : (SMEM + S_F2  + row + (ks - 2) * 32);
            a = __builtin_amdgcn_mfma_f32_16x16x32_bf16(aw, *(const short8*)src, a, 0, 0, 0);
        }
        a1[0] = a;
        epi_relu_lds<1>(a1, wid, 0, h, p16, SMEM + S_X3A, 104);
    }
    __syncthreads();   // B7

    // ============ phase 7: C3B -> X4 ch0..63 rows 0..15 ====================
    if (wid < 4) {
        mfma_tiles<3, 1>((const short8*)(wsp + WC3B), wid, 0, SMEM + S_X3A, 104, lane, a1);
        epi_relu_lds<1>(a1, wid, 0, h, p16, SMEM + S_X4, 104);
    }
    __syncthreads();   // B8

    // ============ phase 8: PN2 -> deeprealfeat =============================
    mfma_tiles<3, 1>((const short8*)(wsp + WPN), wid, 0, SMEM + S_X4, 104, lane, a1);
    {
        int ch0 = wid * 16 + h * 4;
        size_t base = OUT_DEEP + ((size_t)(b * 128 + ch0)) * N_PTS + n0 + p16;
        out[base]             = fmaxf(a1[0].x, 0.f);
        out[base + N_PTS]     = fmaxf(a1[0].y, 0.f);
        out[base + 2 * N_PTS] = fmaxf(a1[0].z, 0.f);
        out[base + 3 * N_PTS] = fmaxf(a1[0].w, 0.f);
    }
}

extern "C" void kernel_launch(void* const* d_in, const int* in_sizes, int n_in,
                              void* d_out, int out_size, void* d_ws, size_t ws_size,
                              hipStream_t stream) {
    const float* img    = (const float*)d_in[0];
    const float* knn    = (const float*)d_in[1];
    const float* pts    = (const float*)d_in[2];
    const float* f2d    = (const float*)d_in[3];
    const float* sift_W = (const float*)d_in[4];
    const float* sift_b = (const float*)d_in[5];
    const float* sift_g = (const float*)d_in[6];
    const float* sift_bt= (const float*)d_in[7];
    const float* c2_W1  = (const float*)d_in[8];
    const float* c2_b1  = (const float*)d_in[9];
    const float* c2_g1  = (const float*)d_in[10];
    const float* c2_bt1 = (const float*)d_in[11];
    const float* c2_W2  = (const float*)d_in[12];
    const float* c2_b2  = (const float*)d_in[13];
    const float* c2_g2  = (const float*)d_in[14];
    const float* c2_bt2 = (const float*)d_in[15];
    const float* lin1_W = (const float*)d_in[16];
    const float* lin1_b = (const float*)d_in[17];
    const float* c3_W1  = (const float*)d_in[18];
    const float* c3_b1  = (const float*)d_in[19];
    const float* c3_g1  = (const float*)d_in[20];
    const float* c3_bt1 = (const float*)d_in[21];
    const float* c3_W2  = (const float*)d_in[22];
    const float* c3_b2  = (const float*)d_in[23];
    const float* c3_g2  = (const float*)d_in[24];
    const float* c3_bt2 = (const float*)d_in[25];
    const float* pn2_W  = (const float*)d_in[26];
    const float* pn2_b  = (const float*)d_in[27];
    const float* pn2_g  = (const float*)d_in[28];
    const float* pn2_bt = (const float*)d_in[29];
    const float* fw1    = (const float*)d_in[30];
    const float* fw2    = (const float*)d_in[31];
    const float* fw3    = (const float*)d_in[32];

    ushort_t* wsp = (ushort_t*)d_ws;
    float* out = (float*)d_out;

    prep_all<<<39, 256, 0, stream>>>(
        sift_W, sift_b, sift_g, sift_bt,
        c2_W1, c2_b1, c2_g1, c2_bt1,
        c2_W2, c2_b2, c2_g2, c2_bt2,
        lin1_W, lin1_b,
        c3_W1, c3_b1, c3_g1, c3_bt1,
        c3_W2, c3_b2, c3_g2, c3_bt2,
        pn2_W, pn2_b, pn2_g, pn2_bt,
        wsp);

    fused_all<<<2048, 512, 0, stream>>>(img, knn, pts, f2d, fw1, fw2, fw3, wsp, out);
}